// Round 5
// baseline (887.375 us; speedup 1.0000x reference)
//
#include <hip/hip_runtime.h>
#include <math.h>

typedef __bf16 bf16x8 __attribute__((ext_vector_type(8)));
typedef float  f32x4  __attribute__((ext_vector_type(4)));

#define NROWS 6272
#define CDIM  768
#define HIDD  3072

#define EPI_BIAS 0
#define EPI_GELU 2
#define EPI_RES  3

__device__ __forceinline__ void gload16(const void* g, void* l) {
    __builtin_amdgcn_global_load_lds(
        (const __attribute__((address_space(1))) void*)(uintptr_t)g,
        (__attribute__((address_space(3))) void*)(uintptr_t)l,
        16, 0, 0);
}

// m204 bijective XCD-chunked swizzle
__device__ __forceinline__ void xcd_swz(int& m, int& n) {
    const int gx = gridDim.x;
    const int nwg = gx * gridDim.y;
    const int orig = blockIdx.x + gx * blockIdx.y;
    const int q = nwg >> 3, r = nwg & 7;
    const int xcd = orig & 7, loc = orig >> 3;
    const int wg = (xcd < r ? xcd * (q + 1) : r * (q + 1) + (xcd - r) * q) + loc;
    m = wg / gx;
    n = wg % gx;
}

// ---------------- weight transpose + cast: W (K x N fp32) -> WT (N x K bf16) ----------------
__global__ __launch_bounds__(256) void transpose_w(const float* __restrict__ W,
                                                   __bf16* __restrict__ WT,
                                                   int K, int N) {
    __shared__ float tile[32][33];
    const int tx = threadIdx.x, ty = threadIdx.y;
    const int kb = blockIdx.y * 32, nb = blockIdx.x * 32;
    #pragma unroll
    for (int r = 0; r < 4; ++r)
        tile[ty + r * 8][tx] = W[(size_t)(kb + ty + r * 8) * N + nb + tx];
    __syncthreads();
    #pragma unroll
    for (int r = 0; r < 4; ++r)
        WT[(size_t)(nb + ty + r * 8) * K + kb + tx] = (__bf16)tile[tx][ty + r * 8];
}

// ---------------- LayerNorm (fp32 in, bf16 out) ----------------
__global__ __launch_bounds__(256) void ln_kernel(const float* __restrict__ x,
                                                 const float* __restrict__ sc,
                                                 const float* __restrict__ bi,
                                                 __bf16* __restrict__ o) {
    const int row = blockIdx.x;
    const float* xr = x + (size_t)row * CDIM;
    __bf16* orow = o + (size_t)row * CDIM;
    const int t = threadIdx.x;

    float v0 = xr[t], v1 = xr[t + 256], v2 = xr[t + 512];
    float s = v0 + v1 + v2;

    __shared__ float sm[8];
    #pragma unroll
    for (int off = 32; off > 0; off >>= 1) s += __shfl_xor(s, off);
    const int wid = t >> 6, lane = t & 63;
    if (lane == 0) sm[wid] = s;
    __syncthreads();
    const float mu = (sm[0] + sm[1] + sm[2] + sm[3]) * (1.0f / 768.0f);

    const float d0 = v0 - mu, d1 = v1 - mu, d2 = v2 - mu;
    float s2 = d0 * d0 + d1 * d1 + d2 * d2;
    #pragma unroll
    for (int off = 32; off > 0; off >>= 1) s2 += __shfl_xor(s2, off);
    if (lane == 0) sm[4 + wid] = s2;
    __syncthreads();
    const float var = (sm[4] + sm[5] + sm[6] + sm[7]) * (1.0f / 768.0f);
    const float r = rsqrtf(var + 1e-6f);

    orow[t]       = (__bf16)(d0 * r * sc[t]       + bi[t]);
    orow[t + 256] = (__bf16)(d1 * r * sc[t + 256] + bi[t + 256]);
    orow[t + 512] = (__bf16)(d2 * r * sc[t + 512] + bi[t + 512]);
}

// ---------------- generic MFMA GEMM, tile BM x BN, BK=32, 4 waves ----------------
template <int EPI, int BM, int BN>
__global__ __launch_bounds__(256) void mm_bf16(const __bf16* __restrict__ A, int lda,
                                               const __bf16* __restrict__ BT,
                                               const float* __restrict__ bias,
                                               const float* __restrict__ gamma,
                                               const float* __restrict__ res, int ldr,
                                               void* __restrict__ outv, int ldo,
                                               int K) {
    constexpr int RF = BM / 32;
    constexpr int CF = BN / 32;
    __shared__ __bf16 As[BM * 32];
    __shared__ __bf16 Bs[BN * 32];
    int mb, nb;
    xcd_swz(mb, nb);
    const int m0 = mb * BM, n0 = nb * BN;

    const int t  = threadIdx.x;
    const int w  = t >> 6;
    const int l  = t & 63;
    const int wm = w >> 1, wn = w & 1;
    const int rsub = t >> 2;
    const int ke   = (t & 3) * 8;
    const int fr = l & 15;
    const int kq = (l >> 4) * 8;

    f32x4 acc[RF][CF];
    #pragma unroll
    for (int i = 0; i < RF; ++i)
        #pragma unroll
        for (int j = 0; j < CF; ++j)
            acc[i][j] = f32x4{0.f, 0.f, 0.f, 0.f};

    const __bf16* gA = A  + (size_t)(m0 + rsub) * lda + ke;
    const __bf16* gB = BT + (size_t)(n0 + rsub) * K   + ke;
    __bf16* lA = &As[w * 512];
    __bf16* lB = &Bs[w * 512];

    for (int k0 = 0; k0 < K; k0 += 32) {
        __syncthreads();
        #pragma unroll
        for (int h = 0; h < BM / 64; ++h)
            gload16(gA + (size_t)(h * 64) * lda + k0, lA + h * 2048);
        #pragma unroll
        for (int h = 0; h < BN / 64; ++h)
            gload16(gB + (size_t)(h * 64) * K + k0, lB + h * 2048);
        __syncthreads();

        bf16x8 av[RF], bv[CF];
        #pragma unroll
        for (int i = 0; i < RF; ++i)
            av[i] = *(const bf16x8*)&As[(wm * (BM / 2) + i * 16 + fr) * 32 + kq];
        #pragma unroll
        for (int j = 0; j < CF; ++j)
            bv[j] = *(const bf16x8*)&Bs[(wn * (BN / 2) + j * 16 + fr) * 32 + kq];
        #pragma unroll
        for (int i = 0; i < RF; ++i)
            #pragma unroll
            for (int j = 0; j < CF; ++j)
                acc[i][j] = __builtin_amdgcn_mfma_f32_16x16x32_bf16(av[i], bv[j], acc[i][j], 0, 0, 0);
    }

    const int row0 = m0 + wm * (BM / 2);
    const int col0 = n0 + wn * (BN / 2);
    #pragma unroll
    for (int i = 0; i < RF; ++i) {
        #pragma unroll
        for (int j = 0; j < CF; ++j) {
            const int col = col0 + j * 16 + fr;
            const float bsv = bias[col];
            #pragma unroll
            for (int r = 0; r < 4; ++r) {
                const int row = row0 + i * 16 + (l >> 4) * 4 + r;
                float z = acc[i][j][r] + bsv;
                if (EPI == EPI_BIAS) {
                    ((__bf16*)outv)[(size_t)row * ldo + col] = (__bf16)z;
                } else if (EPI == EPI_GELU) {
                    const float z3 = z * z * z;
                    z = 0.5f * z * (1.0f + tanhf(0.7978845608028654f * (z + 0.044715f * z3)));
                    ((__bf16*)outv)[(size_t)row * ldo + col] = (__bf16)z;
                } else {  // EPI_RES
                    const float zz = res[(size_t)row * ldr + col] + z * gamma[col];
                    ((float*)outv)[(size_t)row * ldo + col] = zz;
                }
            }
        }
    }
}

// ---------------- persistent gated-CSSM recurrence, v2 ----------------
// 196 blocks x 32 rows, 1024 threads (16 waves -> 4 waves/SIMD iff VGPR<=128).
// hx/hy/u resident in LDS (144 KB, XOR swizzle byte^((row&7)<<4) -> frag reads 2-way free).
// Each wave owns 48 cols x 32 rows (3 col-frags x 2 row-frags, 6 MFMA per k-step).
// W_gate streamed from L2 with explicit 2-deep register prefetch (b0/b1, static names).
#define GROWS 32
__global__ __launch_bounds__(1024) void gate_persist(const __bf16* __restrict__ u,
                                                     const __bf16* __restrict__ WTg,
                                                     const float* __restrict__ b_gate,
                                                     const float* __restrict__ ad,
                                                     const float* __restrict__ br,
                                                     __bf16* __restrict__ hx_out) {
    __shared__ __bf16 hxs[GROWS * 768];
    __shared__ __bf16 hys[GROWS * 768];
    __shared__ __bf16 us [GROWS * 768];

    const int t = threadIdx.x;          // 0..1023
    const int w = t >> 6;               // 0..15
    const int l = t & 63;
    const int fr = l & 15;
    const int q4 = l >> 4;              // 0..3
    const int c0 = w * 48;              // 48 cols per wave
    const int row_base = blockIdx.x * GROWS;

    // stage u -> us & hxs (hx0 = u; t=0 step collapsed), zero hys
    #pragma unroll
    for (int p = 0; p < 3; ++p) {
        const int idx = p * 1024 + t;               // 0..3071
        const int row = idx / 96, c8 = idx % 96;
        const uint4 v = *(const uint4*)&u[(size_t)(row_base + row) * 768 + c8 * 8];
        const int le = (row * 768 + c8 * 8) ^ ((row & 7) << 3);
        *(uint4*)&us[le]  = v;
        *(uint4*)&hxs[le] = v;
        *(uint4*)&hys[le] = make_uint4(0u, 0u, 0u, 0u);
    }
    __syncthreads();

    // per-colfrag constants + step-invariant W pointers
    float bias_c[3], a_c[3], b_c[3];
    const __bf16* wp0 = WTg + (size_t)(c0 +  0 + fr) * 1536 + q4 * 8;
    const __bf16* wp1 = WTg + (size_t)(c0 + 16 + fr) * 1536 + q4 * 8;
    const __bf16* wp2 = WTg + (size_t)(c0 + 32 + fr) * 1536 + q4 * 8;
    #pragma unroll
    for (int cf = 0; cf < 3; ++cf) {
        const int col = c0 + cf * 16 + fr;
        bias_c[cf] = b_gate[col];
        a_c[cf]    = ad[col];
        b_c[cf]    = br[col];
    }

    // A-frag LDS read: row = rf*16+fr, k-elems [k, k+8)
    #define LDSA(buf, rf, k) \
        (*(const bf16x8*)&(buf)[(((rf) * 16 + fr) * 768 + (k) + q4 * 8) ^ ((fr & 7) << 3)])
    #define LOADW(dst, kt) do { \
        dst[0] = *(const bf16x8*)(wp0 + (kt) * 32); \
        dst[1] = *(const bf16x8*)(wp1 + (kt) * 32); \
        dst[2] = *(const bf16x8*)(wp2 + (kt) * 32); } while (0)
    #define MFMA6(avv, bvv) do { \
        __builtin_amdgcn_s_setprio(1); \
        _Pragma("unroll") \
        for (int rf = 0; rf < 2; ++rf) \
            _Pragma("unroll") \
            for (int cf = 0; cf < 3; ++cf) \
                acc[rf][cf] = __builtin_amdgcn_mfma_f32_16x16x32_bf16(avv[rf], bvv[cf], acc[rf][cf], 0, 0, 0); \
        __builtin_amdgcn_s_setprio(0); } while (0)

    for (int ts = 1; ts < 8; ++ts) {
        f32x4 acc[2][3];
        #pragma unroll
        for (int rf = 0; rf < 2; ++rf)
            #pragma unroll
            for (int cf = 0; cf < 3; ++cf)
                acc[rf][cf] = f32x4{0.f, 0.f, 0.f, 0.f};

        bf16x8 b0[3], b1[3], av[2];
        LOADW(b0, 0);
        LOADW(b1, 1);

        // K half 1: A from hxs (W k-index continuous 0..23, prefetch crosses halves)
        for (int kt = 0; kt < 12; kt += 2) {
            av[0] = LDSA(hxs, 0, kt * 32);
            av[1] = LDSA(hxs, 1, kt * 32);
            MFMA6(av, b0);
            LOADW(b0, kt + 2);
            av[0] = LDSA(hxs, 0, (kt + 1) * 32);
            av[1] = LDSA(hxs, 1, (kt + 1) * 32);
            MFMA6(av, b1);
            LOADW(b1, kt + 3);
        }
        // K half 2: A from hys
        for (int kt = 12; kt < 24; kt += 2) {
            av[0] = LDSA(hys, 0, (kt - 12) * 32);
            av[1] = LDSA(hys, 1, (kt - 12) * 32);
            MFMA6(av, b0);
            if (kt + 2 < 24) LOADW(b0, kt + 2);
            av[0] = LDSA(hys, 0, (kt - 11) * 32);
            av[1] = LDSA(hys, 1, (kt - 11) * 32);
            MFMA6(av, b1);
            if (kt + 3 < 24) LOADW(b1, kt + 3);
        }
        __syncthreads();   // all waves done reading old state

        const bool last = (ts == 7);
        #pragma unroll
        for (int rf = 0; rf < 2; ++rf)
            #pragma unroll
            for (int cf = 0; cf < 3; ++cf)
                #pragma unroll
                for (int r = 0; r < 4; ++r) {
                    const int row = rf * 16 + q4 * 4 + r;
                    const int col = c0 + cf * 16 + fr;
                    const int le = (row * 768 + col) ^ ((row & 7) << 3);
                    const float z = acc[rf][cf][r] + bias_c[cf];
                    const float g = 1.0f / (1.0f + __expf(-z));
                    const float hx = (float)hxs[le];
                    const float hy = (float)hys[le];
                    const float nx = g * (a_c[cf] * hx - b_c[cf] * hy) + (float)us[le];
                    if (last) {
                        hx_out[(size_t)(row_base + row) * 768 + col] = (__bf16)nx;
                    } else {
                        hxs[le] = (__bf16)nx;
                        hys[le] = (__bf16)(g * (b_c[cf] * hx + a_c[cf] * hy));
                    }
                }
        __syncthreads();   // updates visible before next step's GEMM
    }
    #undef LDSA
    #undef LOADW
    #undef MFMA6
}

extern "C" void kernel_launch(void* const* d_in, const int* in_sizes, int n_in,
                              void* d_out, int out_size, void* d_ws, size_t ws_size,
                              hipStream_t stream) {
    (void)in_sizes; (void)n_in; (void)out_size;
    const float* x      = (const float*)d_in[0];
    const float* ln1_s  = (const float*)d_in[1];
    const float* ln1_b  = (const float*)d_in[2];
    const float* W_in   = (const float*)d_in[3];
    const float* b_in   = (const float*)d_in[4];
    const float* W_gate = (const float*)d_in[5];
    const float* b_gate = (const float*)d_in[6];
    const float* a_dec  = (const float*)d_in[7];
    const float* b_rot  = (const float*)d_in[8];
    const float* W_out  = (const float*)d_in[9];
    const float* b_out  = (const float*)d_in[10];
    const float* gamma1 = (const float*)d_in[11];
    const float* ln2_s  = (const float*)d_in[12];
    const float* ln2_b  = (const float*)d_in[13];
    const float* W1     = (const float*)d_in[14];
    const float* b1     = (const float*)d_in[15];
    const float* W2     = (const float*)d_in[16];
    const float* b2     = (const float*)d_in[17];
    const float* gamma2 = (const float*)d_in[18];
    float* out = (float*)d_out;

    // ---- workspace layout (bytes), total 100,859,904 ----
    if (ws_size < 100859904) return;
    char* w8 = (char*)d_ws;
    __bf16* WT_in   = (__bf16*)(w8);                 // 768x768  bf16
    __bf16* WT_gate = (__bf16*)(w8 + 1179648);       // 768x1536 bf16
    __bf16* WT_out  = (__bf16*)(w8 + 3538944);       // 768x768  bf16
    __bf16* WT1     = (__bf16*)(w8 + 4718592);       // 3072x768 bf16
    __bf16* WT2     = (__bf16*)(w8 + 9437184);       // 768x3072 bf16
    float*  x1      = (float*)(w8 + 14155776);       // NC fp32
    __bf16* xn      = (__bf16*)(w8 + 33423360);      // NC bf16 (both LN outputs)
    __bf16* u       = (__bf16*)(w8 + 43057152);      // NC bf16
    __bf16* hx_out  = (__bf16*)(w8 + 52690944);      // NC bf16
    __bf16* h       = (__bf16*)(w8 + 62324736);      // NROWS x 3072 bf16

    const dim3 tb(32, 8);
    transpose_w<<<dim3(24, 24), tb, 0, stream>>>(W_in,   WT_in,   768,  768);
    transpose_w<<<dim3(24, 48), tb, 0, stream>>>(W_gate, WT_gate, 1536, 768);
    transpose_w<<<dim3(24, 24), tb, 0, stream>>>(W_out,  WT_out,  768,  768);
    transpose_w<<<dim3(96, 24), tb, 0, stream>>>(W1,     WT1,     768,  3072);
    transpose_w<<<dim3(24, 96), tb, 0, stream>>>(W2,     WT2,     3072, 768);

    const dim3 gC(12, 49);   // N=768 GEMMs: 128x64 tiles, 588 blocks
    const dim3 gH(24, 49);   // GELU: 128x128, 1176 blocks

    // branch 1
    ln_kernel<<<NROWS, 256, 0, stream>>>(x, ln1_s, ln1_b, xn);
    mm_bf16<EPI_BIAS, 128, 64><<<gC, 256, 0, stream>>>(xn, 768, WT_in, b_in,
                                                       nullptr, nullptr, 0, u, 768, 768);
    gate_persist<<<196, 1024, 0, stream>>>(u, WT_gate, b_gate, a_dec, b_rot, hx_out);
    mm_bf16<EPI_RES, 128, 64><<<gC, 256, 0, stream>>>(hx_out, 768, WT_out, b_out,
                                                      gamma1, x, 768, x1, 768, 768);
    // branch 2
    ln_kernel<<<NROWS, 256, 0, stream>>>(x1, ln2_s, ln2_b, xn);
    mm_bf16<EPI_GELU, 128, 128><<<gH, 256, 0, stream>>>(xn, 768, WT1, b1,
                                                        nullptr, nullptr, 0, h, 3072, 768);
    mm_bf16<EPI_RES, 128, 64><<<gC, 256, 0, stream>>>(h, 3072, WT2, b2,
                                                      gamma2, x1, 768, out, 768, 3072);
}

// Round 6
// 874.758 us; speedup vs baseline: 1.0144x; 1.0144x over previous
//
#include <hip/hip_runtime.h>
#include <math.h>

typedef __bf16 bf16x8 __attribute__((ext_vector_type(8)));
typedef float  f32x4  __attribute__((ext_vector_type(4)));

#define NROWS 6272
#define CDIM  768
#define HIDD  3072

#define EPI_BIAS 0
#define EPI_GELU 2
#define EPI_RES  3

__device__ __forceinline__ void gload16(const void* g, void* l) {
    __builtin_amdgcn_global_load_lds(
        (const __attribute__((address_space(1))) void*)(uintptr_t)g,
        (__attribute__((address_space(3))) void*)(uintptr_t)l,
        16, 0, 0);
}

// m204 bijective XCD-chunked swizzle
__device__ __forceinline__ void xcd_swz(int& m, int& n) {
    const int gx = gridDim.x;
    const int nwg = gx * gridDim.y;
    const int orig = blockIdx.x + gx * blockIdx.y;
    const int q = nwg >> 3, r = nwg & 7;
    const int xcd = orig & 7, loc = orig >> 3;
    const int wg = (xcd < r ? xcd * (q + 1) : r * (q + 1) + (xcd - r) * q) + loc;
    m = wg / gx;
    n = wg % gx;
}

// ---------------- weight transpose + cast: W (K x N fp32) -> WT (N x K bf16) ----------------
__global__ __launch_bounds__(256) void transpose_w(const float* __restrict__ W,
                                                   __bf16* __restrict__ WT,
                                                   int K, int N) {
    __shared__ float tile[32][33];
    const int tx = threadIdx.x, ty = threadIdx.y;
    const int kb = blockIdx.y * 32, nb = blockIdx.x * 32;
    #pragma unroll
    for (int r = 0; r < 4; ++r)
        tile[ty + r * 8][tx] = W[(size_t)(kb + ty + r * 8) * N + nb + tx];
    __syncthreads();
    #pragma unroll
    for (int r = 0; r < 4; ++r)
        WT[(size_t)(nb + ty + r * 8) * K + kb + tx] = (__bf16)tile[tx][ty + r * 8];
}

// ---------------- LayerNorm (fp32 in, bf16 out) ----------------
__global__ __launch_bounds__(256) void ln_kernel(const float* __restrict__ x,
                                                 const float* __restrict__ sc,
                                                 const float* __restrict__ bi,
                                                 __bf16* __restrict__ o) {
    const int row = blockIdx.x;
    const float* xr = x + (size_t)row * CDIM;
    __bf16* orow = o + (size_t)row * CDIM;
    const int t = threadIdx.x;

    float v0 = xr[t], v1 = xr[t + 256], v2 = xr[t + 512];
    float s = v0 + v1 + v2;

    __shared__ float sm[8];
    #pragma unroll
    for (int off = 32; off > 0; off >>= 1) s += __shfl_xor(s, off);
    const int wid = t >> 6, lane = t & 63;
    if (lane == 0) sm[wid] = s;
    __syncthreads();
    const float mu = (sm[0] + sm[1] + sm[2] + sm[3]) * (1.0f / 768.0f);

    const float d0 = v0 - mu, d1 = v1 - mu, d2 = v2 - mu;
    float s2 = d0 * d0 + d1 * d1 + d2 * d2;
    #pragma unroll
    for (int off = 32; off > 0; off >>= 1) s2 += __shfl_xor(s2, off);
    if (lane == 0) sm[4 + wid] = s2;
    __syncthreads();
    const float var = (sm[4] + sm[5] + sm[6] + sm[7]) * (1.0f / 768.0f);
    const float r = rsqrtf(var + 1e-6f);

    orow[t]       = (__bf16)(d0 * r * sc[t]       + bi[t]);
    orow[t + 256] = (__bf16)(d1 * r * sc[t + 256] + bi[t + 256]);
    orow[t + 512] = (__bf16)(d2 * r * sc[t + 512] + bi[t + 512]);
}

// ---------------- generic MFMA GEMM, tile BM x BN, BK=32, 4 waves ----------------
template <int EPI, int BM, int BN>
__global__ __launch_bounds__(256) void mm_bf16(const __bf16* __restrict__ A, int lda,
                                               const __bf16* __restrict__ BT,
                                               const float* __restrict__ bias,
                                               const float* __restrict__ gamma,
                                               const float* __restrict__ res, int ldr,
                                               void* __restrict__ outv, int ldo,
                                               int K) {
    constexpr int RF = BM / 32;
    constexpr int CF = BN / 32;
    __shared__ __bf16 As[BM * 32];
    __shared__ __bf16 Bs[BN * 32];
    int mb, nb;
    xcd_swz(mb, nb);
    const int m0 = mb * BM, n0 = nb * BN;

    const int t  = threadIdx.x;
    const int w  = t >> 6;
    const int l  = t & 63;
    const int wm = w >> 1, wn = w & 1;
    const int rsub = t >> 2;
    const int ke   = (t & 3) * 8;
    const int fr = l & 15;
    const int kq = (l >> 4) * 8;

    f32x4 acc[RF][CF];
    #pragma unroll
    for (int i = 0; i < RF; ++i)
        #pragma unroll
        for (int j = 0; j < CF; ++j)
            acc[i][j] = f32x4{0.f, 0.f, 0.f, 0.f};

    const __bf16* gA = A  + (size_t)(m0 + rsub) * lda + ke;
    const __bf16* gB = BT + (size_t)(n0 + rsub) * K   + ke;
    __bf16* lA = &As[w * 512];
    __bf16* lB = &Bs[w * 512];

    for (int k0 = 0; k0 < K; k0 += 32) {
        __syncthreads();
        #pragma unroll
        for (int h = 0; h < BM / 64; ++h)
            gload16(gA + (size_t)(h * 64) * lda + k0, lA + h * 2048);
        #pragma unroll
        for (int h = 0; h < BN / 64; ++h)
            gload16(gB + (size_t)(h * 64) * K + k0, lB + h * 2048);
        __syncthreads();

        bf16x8 av[RF], bv[CF];
        #pragma unroll
        for (int i = 0; i < RF; ++i)
            av[i] = *(const bf16x8*)&As[(wm * (BM / 2) + i * 16 + fr) * 32 + kq];
        #pragma unroll
        for (int j = 0; j < CF; ++j)
            bv[j] = *(const bf16x8*)&Bs[(wn * (BN / 2) + j * 16 + fr) * 32 + kq];
        #pragma unroll
        for (int i = 0; i < RF; ++i)
            #pragma unroll
            for (int j = 0; j < CF; ++j)
                acc[i][j] = __builtin_amdgcn_mfma_f32_16x16x32_bf16(av[i], bv[j], acc[i][j], 0, 0, 0);
    }

    const int row0 = m0 + wm * (BM / 2);
    const int col0 = n0 + wn * (BN / 2);
    #pragma unroll
    for (int i = 0; i < RF; ++i) {
        #pragma unroll
        for (int j = 0; j < CF; ++j) {
            const int col = col0 + j * 16 + fr;
            const float bsv = bias[col];
            #pragma unroll
            for (int r = 0; r < 4; ++r) {
                const int row = row0 + i * 16 + (l >> 4) * 4 + r;
                float z = acc[i][j][r] + bsv;
                if (EPI == EPI_BIAS) {
                    ((__bf16*)outv)[(size_t)row * ldo + col] = (__bf16)z;
                } else if (EPI == EPI_GELU) {
                    const float z3 = z * z * z;
                    z = 0.5f * z * (1.0f + tanhf(0.7978845608028654f * (z + 0.044715f * z3)));
                    ((__bf16*)outv)[(size_t)row * ldo + col] = (__bf16)z;
                } else {  // EPI_RES
                    const float zz = res[(size_t)row * ldr + col] + z * gamma[col];
                    ((float*)outv)[(size_t)row * ldo + col] = zz;
                }
            }
        }
    }
}

// ---------------- persistent gated-CSSM recurrence, v3 ----------------
// 196 blocks x 32 rows, 1024 threads = 16 waves = 4 waves/SIMD (1 block/CU, LDS-bound).
// __launch_bounds__(1024, 4): cap VGPR at 128 (NOT 64 -> round-5's 1.1 GB scratch spill).
// hx/hy/u in LDS (144 KB, XOR swizzle elem^((row&7)<<3): frag reads 2-way = free).
// Each wave: 48 cols x 32 rows (3 col-frags x 2 row-frags). W_gate streamed from L2
// with 2-deep static-named register prefetch (b0/b1).
#define GROWS 32
__global__ __launch_bounds__(1024, 4) void gate_persist(const __bf16* __restrict__ u,
                                                        const __bf16* __restrict__ WTg,
                                                        const float* __restrict__ b_gate,
                                                        const float* __restrict__ ad,
                                                        const float* __restrict__ br,
                                                        __bf16* __restrict__ hx_out) {
    __shared__ __bf16 hxs[GROWS * 768];
    __shared__ __bf16 hys[GROWS * 768];
    __shared__ __bf16 us [GROWS * 768];

    const int t = threadIdx.x;          // 0..1023
    const int w = t >> 6;               // 0..15
    const int l = t & 63;
    const int fr = l & 15;
    const int q4 = l >> 4;              // 0..3
    const int c0 = w * 48;              // 48 cols per wave
    const int row_base = blockIdx.x * GROWS;

    // stage u -> us & hxs (hx0 = u; t=0 step collapsed), zero hys
    #pragma unroll
    for (int p = 0; p < 3; ++p) {
        const int idx = p * 1024 + t;               // 0..3071
        const int row = idx / 96, c8 = idx % 96;
        const uint4 v = *(const uint4*)&u[(size_t)(row_base + row) * 768 + c8 * 8];
        const int le = (row * 768 + c8 * 8) ^ ((row & 7) << 3);
        *(uint4*)&us[le]  = v;
        *(uint4*)&hxs[le] = v;
        *(uint4*)&hys[le] = make_uint4(0u, 0u, 0u, 0u);
    }
    __syncthreads();

    // per-colfrag constants + step-invariant W pointers
    float bias_c[3], a_c[3], b_c[3];
    const __bf16* wp0 = WTg + (size_t)(c0 +  0 + fr) * 1536 + q4 * 8;
    const __bf16* wp1 = WTg + (size_t)(c0 + 16 + fr) * 1536 + q4 * 8;
    const __bf16* wp2 = WTg + (size_t)(c0 + 32 + fr) * 1536 + q4 * 8;
    #pragma unroll
    for (int cf = 0; cf < 3; ++cf) {
        const int col = c0 + cf * 16 + fr;
        bias_c[cf] = b_gate[col];
        a_c[cf]    = ad[col];
        b_c[cf]    = br[col];
    }

    // A-frag LDS read: row = rf*16+fr, k-elems [k, k+8)
    #define LDSA(buf, rf, k) \
        (*(const bf16x8*)&(buf)[(((rf) * 16 + fr) * 768 + (k) + q4 * 8) ^ ((fr & 7) << 3)])
    #define LOADW(dst, kt) do { \
        dst[0] = *(const bf16x8*)(wp0 + (kt) * 32); \
        dst[1] = *(const bf16x8*)(wp1 + (kt) * 32); \
        dst[2] = *(const bf16x8*)(wp2 + (kt) * 32); } while (0)
    #define MFMA6(avv, bvv) do { \
        __builtin_amdgcn_s_setprio(1); \
        _Pragma("unroll") \
        for (int rf = 0; rf < 2; ++rf) \
            _Pragma("unroll") \
            for (int cf = 0; cf < 3; ++cf) \
                acc[rf][cf] = __builtin_amdgcn_mfma_f32_16x16x32_bf16(avv[rf], bvv[cf], acc[rf][cf], 0, 0, 0); \
        __builtin_amdgcn_s_setprio(0); } while (0)

    for (int ts = 1; ts < 8; ++ts) {
        f32x4 acc[2][3];
        #pragma unroll
        for (int rf = 0; rf < 2; ++rf)
            #pragma unroll
            for (int cf = 0; cf < 3; ++cf)
                acc[rf][cf] = f32x4{0.f, 0.f, 0.f, 0.f};

        bf16x8 b0[3], b1[3], av[2];
        LOADW(b0, 0);
        LOADW(b1, 1);

        // K half 1: A from hxs (W k-index continuous 0..23, prefetch crosses halves)
        for (int kt = 0; kt < 12; kt += 2) {
            av[0] = LDSA(hxs, 0, kt * 32);
            av[1] = LDSA(hxs, 1, kt * 32);
            MFMA6(av, b0);
            LOADW(b0, kt + 2);
            av[0] = LDSA(hxs, 0, (kt + 1) * 32);
            av[1] = LDSA(hxs, 1, (kt + 1) * 32);
            MFMA6(av, b1);
            LOADW(b1, kt + 3);
        }
        // K half 2: A from hys
        for (int kt = 12; kt < 24; kt += 2) {
            av[0] = LDSA(hys, 0, (kt - 12) * 32);
            av[1] = LDSA(hys, 1, (kt - 12) * 32);
            MFMA6(av, b0);
            if (kt + 2 < 24) LOADW(b0, kt + 2);
            av[0] = LDSA(hys, 0, (kt - 11) * 32);
            av[1] = LDSA(hys, 1, (kt - 11) * 32);
            MFMA6(av, b1);
            if (kt + 3 < 24) LOADW(b1, kt + 3);
        }
        __syncthreads();   // all waves done reading old state

        const bool last = (ts == 7);
        #pragma unroll
        for (int rf = 0; rf < 2; ++rf)
            #pragma unroll
            for (int cf = 0; cf < 3; ++cf)
                #pragma unroll
                for (int r = 0; r < 4; ++r) {
                    const int row = rf * 16 + q4 * 4 + r;
                    const int col = c0 + cf * 16 + fr;
                    const int le = (row * 768 + col) ^ ((row & 7) << 3);
                    const float z = acc[rf][cf][r] + bias_c[cf];
                    const float g = 1.0f / (1.0f + __expf(-z));
                    const float hx = (float)hxs[le];
                    const float hy = (float)hys[le];
                    const float nx = g * (a_c[cf] * hx - b_c[cf] * hy) + (float)us[le];
                    if (last) {
                        hx_out[(size_t)(row_base + row) * 768 + col] = (__bf16)nx;
                    } else {
                        hxs[le] = (__bf16)nx;
                        hys[le] = (__bf16)(g * (b_c[cf] * hx + a_c[cf] * hy));
                    }
                }
        __syncthreads();   // updates visible before next step's GEMM
    }
    #undef LDSA
    #undef LOADW
    #undef MFMA6
}

extern "C" void kernel_launch(void* const* d_in, const int* in_sizes, int n_in,
                              void* d_out, int out_size, void* d_ws, size_t ws_size,
                              hipStream_t stream) {
    (void)in_sizes; (void)n_in; (void)out_size;
    const float* x      = (const float*)d_in[0];
    const float* ln1_s  = (const float*)d_in[1];
    const float* ln1_b  = (const float*)d_in[2];
    const float* W_in   = (const float*)d_in[3];
    const float* b_in   = (const float*)d_in[4];
    const float* W_gate = (const float*)d_in[5];
    const float* b_gate = (const float*)d_in[6];
    const float* a_dec  = (const float*)d_in[7];
    const float* b_rot  = (const float*)d_in[8];
    const float* W_out  = (const float*)d_in[9];
    const float* b_out  = (const float*)d_in[10];
    const float* gamma1 = (const float*)d_in[11];
    const float* ln2_s  = (const float*)d_in[12];
    const float* ln2_b  = (const float*)d_in[13];
    const float* W1     = (const float*)d_in[14];
    const float* b1     = (const float*)d_in[15];
    const float* W2     = (const float*)d_in[16];
    const float* b2     = (const float*)d_in[17];
    const float* gamma2 = (const float*)d_in[18];
    float* out = (float*)d_out;

    // ---- workspace layout (bytes), total 100,859,904 ----
    if (ws_size < 100859904) return;
    char* w8 = (char*)d_ws;
    __bf16* WT_in   = (__bf16*)(w8);                 // 768x768  bf16
    __bf16* WT_gate = (__bf16*)(w8 + 1179648);       // 768x1536 bf16
    __bf16* WT_out  = (__bf16*)(w8 + 3538944);       // 768x768  bf16
    __bf16* WT1     = (__bf16*)(w8 + 4718592);       // 3072x768 bf16
    __bf16* WT2     = (__bf16*)(w8 + 9437184);       // 768x3072 bf16
    float*  x1      = (float*)(w8 + 14155776);       // NC fp32
    __bf16* xn      = (__bf16*)(w8 + 33423360);      // NC bf16 (both LN outputs)
    __bf16* u       = (__bf16*)(w8 + 43057152);      // NC bf16
    __bf16* hx_out  = (__bf16*)(w8 + 52690944);      // NC bf16
    __bf16* h       = (__bf16*)(w8 + 62324736);      // NROWS x 3072 bf16

    const dim3 tb(32, 8);
    transpose_w<<<dim3(24, 24), tb, 0, stream>>>(W_in,   WT_in,   768,  768);
    transpose_w<<<dim3(24, 48), tb, 0, stream>>>(W_gate, WT_gate, 1536, 768);
    transpose_w<<<dim3(24, 24), tb, 0, stream>>>(W_out,  WT_out,  768,  768);
    transpose_w<<<dim3(96, 24), tb, 0, stream>>>(W1,     WT1,     768,  3072);
    transpose_w<<<dim3(24, 96), tb, 0, stream>>>(W2,     WT2,     3072, 768);

    const dim3 gC(12, 98);   // N=768 GEMMs: 64x64 tiles, 1176 blocks (4.6/CU)
    const dim3 gH(24, 49);   // GELU: 128x128, 1176 blocks

    // branch 1
    ln_kernel<<<NROWS, 256, 0, stream>>>(x, ln1_s, ln1_b, xn);
    mm_bf16<EPI_BIAS, 64, 64><<<gC, 256, 0, stream>>>(xn, 768, WT_in, b_in,
                                                      nullptr, nullptr, 0, u, 768, 768);
    gate_persist<<<196, 1024, 0, stream>>>(u, WT_gate, b_gate, a_dec, b_rot, hx_out);
    mm_bf16<EPI_RES, 64, 64><<<gC, 256, 0, stream>>>(hx_out, 768, WT_out, b_out,
                                                     gamma1, x, 768, x1, 768, 768);
    // branch 2
    ln_kernel<<<NROWS, 256, 0, stream>>>(x1, ln2_s, ln2_b, xn);
    mm_bf16<EPI_GELU, 128, 128><<<gH, 256, 0, stream>>>(xn, 768, WT1, b1,
                                                        nullptr, nullptr, 0, h, 3072, 768);
    mm_bf16<EPI_RES, 64, 64><<<gC, 256, 0, stream>>>(h, 3072, WT2, b2,
                                                     gamma2, x1, 768, out, 768, 3072);
}

// Round 7
// 584.310 us; speedup vs baseline: 1.5187x; 1.4971x over previous
//
#include <hip/hip_runtime.h>
#include <math.h>

typedef __bf16 bf16x8 __attribute__((ext_vector_type(8)));
typedef float  f32x4  __attribute__((ext_vector_type(4)));

#define NROWS 6272
#define CDIM  768
#define HIDD  3072

#define EPI_BIAS 0
#define EPI_GELU 2
#define EPI_RES  3

__device__ __forceinline__ void gload16(const void* g, void* l) {
    __builtin_amdgcn_global_load_lds(
        (const __attribute__((address_space(1))) void*)(uintptr_t)g,
        (__attribute__((address_space(3))) void*)(uintptr_t)l,
        16, 0, 0);
}

// m204 bijective XCD-chunked swizzle
__device__ __forceinline__ void xcd_swz(int& m, int& n) {
    const int gx = gridDim.x;
    const int nwg = gx * gridDim.y;
    const int orig = blockIdx.x + gx * blockIdx.y;
    const int q = nwg >> 3, r = nwg & 7;
    const int xcd = orig & 7, loc = orig >> 3;
    const int wg = (xcd < r ? xcd * (q + 1) : r * (q + 1) + (xcd - r) * q) + loc;
    m = wg / gx;
    n = wg % gx;
}

// ---- shared GEMM core: BM x BN tile, BK=32, 4 waves, verified m97 fragment maps ----
template <int BM, int BN>
__device__ __forceinline__ void gemm_core(const __bf16* __restrict__ A, int lda,
                                          const __bf16* __restrict__ BT, int K,
                                          int m0, int n0,
                                          __bf16* As, __bf16* Bs,
                                          f32x4 acc[BM / 32][BN / 32]) {
    constexpr int RF = BM / 32;
    constexpr int CF = BN / 32;
    const int t  = threadIdx.x;
    const int w  = t >> 6;
    const int l  = t & 63;
    const int wm = w >> 1, wn = w & 1;
    const int rsub = t >> 2;
    const int ke   = (t & 3) * 8;
    const int fr = l & 15;
    const int kq = (l >> 4) * 8;

    const __bf16* gA = A  + (size_t)(m0 + rsub) * lda + ke;
    const __bf16* gB = BT + (size_t)(n0 + rsub) * K   + ke;
    __bf16* lA = &As[w * 512];
    __bf16* lB = &Bs[w * 512];

    for (int k0 = 0; k0 < K; k0 += 32) {
        __syncthreads();
        #pragma unroll
        for (int h = 0; h < BM / 64; ++h)
            gload16(gA + (size_t)(h * 64) * lda + k0, lA + h * 2048);
        #pragma unroll
        for (int h = 0; h < BN / 64; ++h)
            gload16(gB + (size_t)(h * 64) * K + k0, lB + h * 2048);
        __syncthreads();

        bf16x8 av[RF], bv[CF];
        #pragma unroll
        for (int i = 0; i < RF; ++i)
            av[i] = *(const bf16x8*)&As[(wm * (BM / 2) + i * 16 + fr) * 32 + kq];
        #pragma unroll
        for (int j = 0; j < CF; ++j)
            bv[j] = *(const bf16x8*)&Bs[(wn * (BN / 2) + j * 16 + fr) * 32 + kq];
        #pragma unroll
        for (int i = 0; i < RF; ++i)
            #pragma unroll
            for (int j = 0; j < CF; ++j)
                acc[i][j] = __builtin_amdgcn_mfma_f32_16x16x32_bf16(av[i], bv[j], acc[i][j], 0, 0, 0);
    }
}

// ---------------- all weight transposes in ONE launch ----------------
// W (K x N fp32) -> WT (N x K bf16), 32x32 tiles, block (32,8)
__global__ __launch_bounds__(256) void transpose_all(const float* __restrict__ W_in,
                                                     const float* __restrict__ W_gate,
                                                     const float* __restrict__ W_out,
                                                     const float* __restrict__ W1,
                                                     const float* __restrict__ W2,
                                                     __bf16* __restrict__ WT_in,
                                                     __bf16* __restrict__ WT_gate,
                                                     __bf16* __restrict__ WT_out,
                                                     __bf16* __restrict__ WT1,
                                                     __bf16* __restrict__ WT2) {
    const int bid = blockIdx.x;
    const float* W; __bf16* WT; int K, N, gx, local;
    if (bid < 576)        { W = W_in;   WT = WT_in;   K = 768;  N = 768;  gx = 24; local = bid; }
    else if (bid < 1728)  { W = W_gate; WT = WT_gate; K = 1536; N = 768;  gx = 24; local = bid - 576; }
    else if (bid < 2304)  { W = W_out;  WT = WT_out;  K = 768;  N = 768;  gx = 24; local = bid - 1728; }
    else if (bid < 4608)  { W = W1;     WT = WT1;     K = 768;  N = 3072; gx = 96; local = bid - 2304; }
    else                  { W = W2;     WT = WT2;     K = 3072; N = 768;  gx = 24; local = bid - 4608; }
    const int nb = (local % gx) * 32;
    const int kb = (local / gx) * 32;

    __shared__ float tile[32][33];
    const int tx = threadIdx.x, ty = threadIdx.y;
    #pragma unroll
    for (int r = 0; r < 4; ++r)
        tile[ty + r * 8][tx] = W[(size_t)(kb + ty + r * 8) * N + nb + tx];
    __syncthreads();
    #pragma unroll
    for (int r = 0; r < 4; ++r)
        WT[(size_t)(nb + ty + r * 8) * K + kb + tx] = (__bf16)tile[tx][ty + r * 8];
}

// ---------------- LayerNorm (fp32 in, bf16 out) ----------------
__global__ __launch_bounds__(256) void ln_kernel(const float* __restrict__ x,
                                                 const float* __restrict__ sc,
                                                 const float* __restrict__ bi,
                                                 __bf16* __restrict__ o) {
    const int row = blockIdx.x;
    const float* xr = x + (size_t)row * CDIM;
    __bf16* orow = o + (size_t)row * CDIM;
    const int t = threadIdx.x;

    float v0 = xr[t], v1 = xr[t + 256], v2 = xr[t + 512];
    float s = v0 + v1 + v2;

    __shared__ float sm[8];
    #pragma unroll
    for (int off = 32; off > 0; off >>= 1) s += __shfl_xor(s, off);
    const int wid = t >> 6, lane = t & 63;
    if (lane == 0) sm[wid] = s;
    __syncthreads();
    const float mu = (sm[0] + sm[1] + sm[2] + sm[3]) * (1.0f / 768.0f);

    const float d0 = v0 - mu, d1 = v1 - mu, d2 = v2 - mu;
    float s2 = d0 * d0 + d1 * d1 + d2 * d2;
    #pragma unroll
    for (int off = 32; off > 0; off >>= 1) s2 += __shfl_xor(s2, off);
    if (lane == 0) sm[4 + wid] = s2;
    __syncthreads();
    const float var = (sm[4] + sm[5] + sm[6] + sm[7]) * (1.0f / 768.0f);
    const float r = rsqrtf(var + 1e-6f);

    orow[t]       = (__bf16)(d0 * r * sc[t]       + bi[t]);
    orow[t + 256] = (__bf16)(d1 * r * sc[t + 256] + bi[t + 256]);
    orow[t + 512] = (__bf16)(d2 * r * sc[t + 512] + bi[t + 512]);
}

// ---------------- generic MFMA GEMM with epilogues ----------------
template <int EPI, int BM, int BN>
__global__ __launch_bounds__(256) void mm_bf16(const __bf16* __restrict__ A, int lda,
                                               const __bf16* __restrict__ BT,
                                               const float* __restrict__ bias,
                                               const float* __restrict__ gamma,
                                               const float* __restrict__ res, int ldr,
                                               void* __restrict__ outv, int ldo,
                                               int K) {
    constexpr int RF = BM / 32;
    constexpr int CF = BN / 32;
    __shared__ __bf16 As[BM * 32];
    __shared__ __bf16 Bs[BN * 32];
    int mb, nb;
    xcd_swz(mb, nb);
    const int m0 = mb * BM, n0 = nb * BN;

    f32x4 acc[RF][CF];
    #pragma unroll
    for (int i = 0; i < RF; ++i)
        #pragma unroll
        for (int j = 0; j < CF; ++j)
            acc[i][j] = f32x4{0.f, 0.f, 0.f, 0.f};

    gemm_core<BM, BN>(A, lda, BT, K, m0, n0, As, Bs, acc);

    const int l = threadIdx.x & 63;
    const int w = threadIdx.x >> 6;
    const int wm = w >> 1, wn = w & 1;
    const int fr = l & 15;
    const int row0 = m0 + wm * (BM / 2);
    const int col0 = n0 + wn * (BN / 2);
    #pragma unroll
    for (int i = 0; i < RF; ++i) {
        #pragma unroll
        for (int j = 0; j < CF; ++j) {
            const int col = col0 + j * 16 + fr;
            const float bsv = bias[col];
            #pragma unroll
            for (int r = 0; r < 4; ++r) {
                const int row = row0 + i * 16 + (l >> 4) * 4 + r;
                float z = acc[i][j][r] + bsv;
                if (EPI == EPI_BIAS) {
                    ((__bf16*)outv)[(size_t)row * ldo + col] = (__bf16)z;
                } else if (EPI == EPI_GELU) {
                    const float z3 = z * z * z;
                    z = 0.5f * z * (1.0f + tanhf(0.7978845608028654f * (z + 0.044715f * z3)));
                    ((__bf16*)outv)[(size_t)row * ldo + col] = (__bf16)z;
                } else {  // EPI_RES
                    const float zz = res[(size_t)row * ldr + col] + z * gamma[col];
                    ((float*)outv)[(size_t)row * ldo + col] = zz;
                }
            }
        }
    }
}

// ---------------- fused gate GEMM + sigmoid + opponent state update ----------------
// Reads hxy_cur (A, lda=1536, K=1536), writes hxy_next (ping-pong: no cross-block race).
template <bool LAST>
__global__ __launch_bounds__(256) void gate_step(const __bf16* __restrict__ hxy_cur,
                                                 const __bf16* __restrict__ WT_gate,
                                                 const float* __restrict__ b_gate,
                                                 const __bf16* __restrict__ u,
                                                 const float* __restrict__ ad,
                                                 const float* __restrict__ br,
                                                 __bf16* __restrict__ hxy_next) {
    constexpr int BM = 64, BN = 64;
    __shared__ __bf16 As[BM * 32];
    __shared__ __bf16 Bs[BN * 32];
    int mb, nb;
    xcd_swz(mb, nb);
    const int m0 = mb * BM, n0 = nb * BN;

    f32x4 acc[2][2];
    #pragma unroll
    for (int i = 0; i < 2; ++i)
        #pragma unroll
        for (int j = 0; j < 2; ++j)
            acc[i][j] = f32x4{0.f, 0.f, 0.f, 0.f};

    gemm_core<BM, BN>(hxy_cur, 1536, WT_gate, 1536, m0, n0, As, Bs, acc);

    const int l = threadIdx.x & 63;
    const int w = threadIdx.x >> 6;
    const int wm = w >> 1, wn = w & 1;
    const int fr = l & 15;
    const int row0 = m0 + wm * 32;
    const int col0 = n0 + wn * 32;
    #pragma unroll
    for (int i = 0; i < 2; ++i) {
        #pragma unroll
        for (int j = 0; j < 2; ++j) {
            const int col = col0 + j * 16 + fr;
            const float bg = b_gate[col];
            const float av = ad[col];
            const float bv = br[col];
            #pragma unroll
            for (int r = 0; r < 4; ++r) {
                const int row = row0 + i * 16 + (l >> 4) * 4 + r;
                float z = acc[i][j][r] + bg;
                z = 1.0f / (1.0f + __expf(-z));
                const size_t base = (size_t)row * 1536 + col;
                const float hx = (float)hxy_cur[base];
                const float hy = (float)hxy_cur[base + 768];
                const float uf = (float)u[(size_t)row * 768 + col];
                hxy_next[base] = (__bf16)(z * (av * hx - bv * hy) + uf);
                if (!LAST)
                    hxy_next[base + 768] = (__bf16)(z * (bv * hx + av * hy));
            }
        }
    }
}

// ---------------- recurrence init: hx0 = u, hy0 = 0 (t=0 collapsed) ----------------
__global__ __launch_bounds__(256) void init_state(const __bf16* __restrict__ u,
                                                  __bf16* __restrict__ hxy) {
    const int i = blockIdx.x * 256 + threadIdx.x;   // over NC/8
    const int row = i / 96, c8 = i % 96;
    const bf16x8 uv = *(const bf16x8*)&u[(size_t)i * 8];
    *(bf16x8*)&hxy[(size_t)row * 1536 + c8 * 8] = uv;
    *(uint4*)&hxy[(size_t)row * 1536 + 768 + c8 * 8] = make_uint4(0u, 0u, 0u, 0u);
}

extern "C" void kernel_launch(void* const* d_in, const int* in_sizes, int n_in,
                              void* d_out, int out_size, void* d_ws, size_t ws_size,
                              hipStream_t stream) {
    (void)in_sizes; (void)n_in; (void)out_size;
    const float* x      = (const float*)d_in[0];
    const float* ln1_s  = (const float*)d_in[1];
    const float* ln1_b  = (const float*)d_in[2];
    const float* W_in   = (const float*)d_in[3];
    const float* b_in   = (const float*)d_in[4];
    const float* W_gate = (const float*)d_in[5];
    const float* b_gate = (const float*)d_in[6];
    const float* a_dec  = (const float*)d_in[7];
    const float* b_rot  = (const float*)d_in[8];
    const float* W_out  = (const float*)d_in[9];
    const float* b_out  = (const float*)d_in[10];
    const float* gamma1 = (const float*)d_in[11];
    const float* ln2_s  = (const float*)d_in[12];
    const float* ln2_b  = (const float*)d_in[13];
    const float* W1     = (const float*)d_in[14];
    const float* b1     = (const float*)d_in[15];
    const float* W2     = (const float*)d_in[16];
    const float* b2     = (const float*)d_in[17];
    const float* gamma2 = (const float*)d_in[18];
    float* out = (float*)d_out;

    // ---- workspace layout (bytes) ----
    if (ws_size < 92000000) return;
    char* w8 = (char*)d_ws;
    __bf16* WT_in   = (__bf16*)(w8);                 // 768x768  bf16
    __bf16* WT_gate = (__bf16*)(w8 + 1179648);       // 768x1536 bf16
    __bf16* WT_out  = (__bf16*)(w8 + 3538944);       // 768x768  bf16
    __bf16* WT1     = (__bf16*)(w8 + 4718592);       // 3072x768 bf16
    __bf16* WT2     = (__bf16*)(w8 + 9437184);       // 768x3072 bf16
    float*  x1      = (float*)(w8 + 14155776);       // NC fp32
    __bf16* xn      = (__bf16*)(w8 + 33423360);      // NC bf16 (both LN outputs)
    __bf16* u       = (__bf16*)(w8 + 43057152);      // NC bf16
    __bf16* hxy_a   = (__bf16*)(w8 + 52690944);      // NROWSx1536 bf16
    __bf16* hxy_b   = (__bf16*)(w8 + 71958528);      // NROWSx1536 bf16
    __bf16* h       = (__bf16*)(w8 + 52690944);      // NROWSx3072 bf16 (overlays hxy, dead by then)

    transpose_all<<<6912, dim3(32, 8), 0, stream>>>(W_in, W_gate, W_out, W1, W2,
                                                    WT_in, WT_gate, WT_out, WT1, WT2);

    const dim3 gC(12, 98);   // N=768 GEMMs: 64x64 tiles, 1176 blocks (4.6/CU)
    const dim3 gH(24, 49);   // GELU: 128x128, 1176 blocks
    const int eb = 2352;     // NC/8/256

    // branch 1
    ln_kernel<<<NROWS, 256, 0, stream>>>(x, ln1_s, ln1_b, xn);
    mm_bf16<EPI_BIAS, 64, 64><<<gC, 256, 0, stream>>>(xn, 768, WT_in, b_in,
                                                      nullptr, nullptr, 0, u, 768, 768);
    init_state<<<eb, 256, 0, stream>>>(u, hxy_a);
    __bf16* cur = hxy_a;
    __bf16* nxt = hxy_b;
    for (int ts = 1; ts < 8; ++ts) {
        if (ts == 7)
            gate_step<true><<<gC, 256, 0, stream>>>(cur, WT_gate, b_gate, u, a_dec, b_rot, nxt);
        else
            gate_step<false><<<gC, 256, 0, stream>>>(cur, WT_gate, b_gate, u, a_dec, b_rot, nxt);
        __bf16* tmp = cur; cur = nxt; nxt = tmp;
    }
    // x1 = x + (hx @ W_out + b_out) * gamma1   (hx = first 768 cols of cur, lda 1536)
    mm_bf16<EPI_RES, 64, 64><<<gC, 256, 0, stream>>>(cur, 1536, WT_out, b_out,
                                                     gamma1, x, 768, x1, 768, 768);
    // branch 2
    ln_kernel<<<NROWS, 256, 0, stream>>>(x1, ln2_s, ln2_b, xn);
    mm_bf16<EPI_GELU, 128, 128><<<gH, 256, 0, stream>>>(xn, 768, WT1, b1,
                                                        nullptr, nullptr, 0, h, 3072, 768);
    mm_bf16<EPI_RES, 64, 64><<<gC, 256, 0, stream>>>(h, 3072, WT2, b2,
                                                     gamma2, x1, 768, out, 768, 3072);
}

// Round 8
// 569.426 us; speedup vs baseline: 1.5584x; 1.0261x over previous
//
#include <hip/hip_runtime.h>
#include <math.h>

typedef __bf16 bf16x8 __attribute__((ext_vector_type(8)));
typedef float  f32x4  __attribute__((ext_vector_type(4)));

#define NROWS 6272
#define CDIM  768
#define HIDD  3072

#define EPI_UINIT 0
#define EPI_GELU  2
#define EPI_RES   3

__device__ __forceinline__ void gload16(const void* g, void* l) {
    __builtin_amdgcn_global_load_lds(
        (const __attribute__((address_space(1))) void*)(uintptr_t)g,
        (__attribute__((address_space(3))) void*)(uintptr_t)l,
        16, 0, 0);
}

// m204 bijective XCD-chunked swizzle
__device__ __forceinline__ void xcd_swz(int& m, int& n) {
    const int gx = gridDim.x;
    const int nwg = gx * gridDim.y;
    const int orig = blockIdx.x + gx * blockIdx.y;
    const int q = nwg >> 3, r = nwg & 7;
    const int xcd = orig & 7, loc = orig >> 3;
    const int wg = (xcd < r ? xcd * (q + 1) : r * (q + 1) + (xcd - r) * q) + loc;
    m = wg / gx;
    n = wg % gx;
}

// ---- shared GEMM core, v2: BK=32, DOUBLE-BUFFERED LDS, depth-1 pipeline ----
// Stage tile k+1 is issued right after the barrier, then tile k is computed; the
// single per-iter __syncthreads() drains loads issued a full compute-phase earlier.
// As/Bs must be sized 2*BM*32 / 2*BN*32. Verified m97 fragment maps.
template <int BM, int BN>
__device__ __forceinline__ void gemm_core(const __bf16* __restrict__ A, int lda,
                                          const __bf16* __restrict__ BT, int K,
                                          int m0, int n0,
                                          __bf16* As, __bf16* Bs,
                                          f32x4 acc[BM / 32][BN / 32]) {
    constexpr int RF = BM / 32;
    constexpr int CF = BN / 32;
    constexpr int ASZ = BM * 32;
    constexpr int BSZ = BN * 32;
    const int t  = threadIdx.x;
    const int w  = t >> 6;
    const int l  = t & 63;
    const int wm = w >> 1, wn = w & 1;
    const int rsub = t >> 2;
    const int ke   = (t & 3) * 8;
    const int fr = l & 15;
    const int kq = (l >> 4) * 8;

    const __bf16* gA = A  + (size_t)(m0 + rsub) * lda + ke;
    const __bf16* gB = BT + (size_t)(n0 + rsub) * K   + ke;

    // prologue: stage tile 0 into buffer 0
    #pragma unroll
    for (int h = 0; h < BM / 64; ++h)
        gload16(gA + (size_t)(h * 64) * lda, As + w * 512 + h * 2048);
    #pragma unroll
    for (int h = 0; h < BN / 64; ++h)
        gload16(gB + (size_t)(h * 64) * K, Bs + w * 512 + h * 2048);

    const int NT = K >> 5;
    #pragma unroll 2
    for (int kt = 0; kt < NT; ++kt) {
        const int cur = kt & 1;
        __syncthreads();   // buf[cur] staged (prologue / prev iter); prev reads drained
        if (kt + 1 < NT) {
            const int k0 = (kt + 1) * 32;
            const int nb = cur ^ 1;
            #pragma unroll
            for (int h = 0; h < BM / 64; ++h)
                gload16(gA + (size_t)(h * 64) * lda + k0, As + nb * ASZ + w * 512 + h * 2048);
            #pragma unroll
            for (int h = 0; h < BN / 64; ++h)
                gload16(gB + (size_t)(h * 64) * K + k0, Bs + nb * BSZ + w * 512 + h * 2048);
        }
        const __bf16* cA = As + cur * ASZ;
        const __bf16* cB = Bs + cur * BSZ;
        bf16x8 av[RF], bv[CF];
        #pragma unroll
        for (int i = 0; i < RF; ++i)
            av[i] = *(const bf16x8*)&cA[(wm * (BM / 2) + i * 16 + fr) * 32 + kq];
        #pragma unroll
        for (int j = 0; j < CF; ++j)
            bv[j] = *(const bf16x8*)&cB[(wn * (BN / 2) + j * 16 + fr) * 32 + kq];
        #pragma unroll
        for (int i = 0; i < RF; ++i)
            #pragma unroll
            for (int j = 0; j < CF; ++j)
                acc[i][j] = __builtin_amdgcn_mfma_f32_16x16x32_bf16(av[i], bv[j], acc[i][j], 0, 0, 0);
    }
}

// ---------------- all weight transposes in ONE launch ----------------
__global__ __launch_bounds__(256) void transpose_all(const float* __restrict__ W_in,
                                                     const float* __restrict__ W_gate,
                                                     const float* __restrict__ W_out,
                                                     const float* __restrict__ W1,
                                                     const float* __restrict__ W2,
                                                     __bf16* __restrict__ WT_in,
                                                     __bf16* __restrict__ WT_gate,
                                                     __bf16* __restrict__ WT_out,
                                                     __bf16* __restrict__ WT1,
                                                     __bf16* __restrict__ WT2) {
    const int bid = blockIdx.x;
    const float* W; __bf16* WT; int K, N, gx, local;
    if (bid < 576)        { W = W_in;   WT = WT_in;   K = 768;  N = 768;  gx = 24; local = bid; }
    else if (bid < 1728)  { W = W_gate; WT = WT_gate; K = 1536; N = 768;  gx = 24; local = bid - 576; }
    else if (bid < 2304)  { W = W_out;  WT = WT_out;  K = 768;  N = 768;  gx = 24; local = bid - 1728; }
    else if (bid < 4608)  { W = W1;     WT = WT1;     K = 768;  N = 3072; gx = 96; local = bid - 2304; }
    else                  { W = W2;     WT = WT2;     K = 3072; N = 768;  gx = 24; local = bid - 4608; }
    const int nb = (local % gx) * 32;
    const int kb = (local / gx) * 32;

    __shared__ float tile[32][33];
    const int tx = threadIdx.x, ty = threadIdx.y;
    #pragma unroll
    for (int r = 0; r < 4; ++r)
        tile[ty + r * 8][tx] = W[(size_t)(kb + ty + r * 8) * N + nb + tx];
    __syncthreads();
    #pragma unroll
    for (int r = 0; r < 4; ++r)
        WT[(size_t)(nb + ty + r * 8) * K + kb + tx] = (__bf16)tile[tx][ty + r * 8];
}

// ---------------- LayerNorm (fp32 in, bf16 out) ----------------
__global__ __launch_bounds__(256) void ln_kernel(const float* __restrict__ x,
                                                 const float* __restrict__ sc,
                                                 const float* __restrict__ bi,
                                                 __bf16* __restrict__ o) {
    const int row = blockIdx.x;
    const float* xr = x + (size_t)row * CDIM;
    __bf16* orow = o + (size_t)row * CDIM;
    const int t = threadIdx.x;

    float v0 = xr[t], v1 = xr[t + 256], v2 = xr[t + 512];
    float s = v0 + v1 + v2;

    __shared__ float sm[8];
    #pragma unroll
    for (int off = 32; off > 0; off >>= 1) s += __shfl_xor(s, off);
    const int wid = t >> 6, lane = t & 63;
    if (lane == 0) sm[wid] = s;
    __syncthreads();
    const float mu = (sm[0] + sm[1] + sm[2] + sm[3]) * (1.0f / 768.0f);

    const float d0 = v0 - mu, d1 = v1 - mu, d2 = v2 - mu;
    float s2 = d0 * d0 + d1 * d1 + d2 * d2;
    #pragma unroll
    for (int off = 32; off > 0; off >>= 1) s2 += __shfl_xor(s2, off);
    if (lane == 0) sm[4 + wid] = s2;
    __syncthreads();
    const float var = (sm[4] + sm[5] + sm[6] + sm[7]) * (1.0f / 768.0f);
    const float r = rsqrtf(var + 1e-6f);

    orow[t]       = (__bf16)(d0 * r * sc[t]       + bi[t]);
    orow[t + 256] = (__bf16)(d1 * r * sc[t + 256] + bi[t + 256]);
    orow[t + 512] = (__bf16)(d2 * r * sc[t + 512] + bi[t + 512]);
}

// ---------------- generic MFMA GEMM with epilogues ----------------
// EPI_UINIT: out(bf16)=z AND hxy0 hx=z, hy=0 (fused init_state)
// EPI_GELU : out(bf16)=z*sigmoid(2c(z+0.044715 z^3))  (tanh-gelu via sigmoid)
// EPI_RES  : out(f32)=res + z*gamma
template <int EPI, int BM, int BN>
__global__ __launch_bounds__(256) void mm_bf16(const __bf16* __restrict__ A, int lda,
                                               const __bf16* __restrict__ BT,
                                               const float* __restrict__ bias,
                                               const float* __restrict__ gamma,
                                               const float* __restrict__ res, int ldr,
                                               void* __restrict__ outv, int ldo,
                                               int K, __bf16* __restrict__ hxy0) {
    constexpr int RF = BM / 32;
    constexpr int CF = BN / 32;
    __shared__ __bf16 As[2 * BM * 32];
    __shared__ __bf16 Bs[2 * BN * 32];
    int mb, nb;
    xcd_swz(mb, nb);
    const int m0 = mb * BM, n0 = nb * BN;

    f32x4 acc[RF][CF];
    #pragma unroll
    for (int i = 0; i < RF; ++i)
        #pragma unroll
        for (int j = 0; j < CF; ++j)
            acc[i][j] = f32x4{0.f, 0.f, 0.f, 0.f};

    gemm_core<BM, BN>(A, lda, BT, K, m0, n0, As, Bs, acc);

    const int l = threadIdx.x & 63;
    const int w = threadIdx.x >> 6;
    const int wm = w >> 1, wn = w & 1;
    const int fr = l & 15;
    const int row0 = m0 + wm * (BM / 2);
    const int col0 = n0 + wn * (BN / 2);
    #pragma unroll
    for (int i = 0; i < RF; ++i) {
        #pragma unroll
        for (int j = 0; j < CF; ++j) {
            const int col = col0 + j * 16 + fr;
            const float bsv = bias[col];
            #pragma unroll
            for (int r = 0; r < 4; ++r) {
                const int row = row0 + i * 16 + (l >> 4) * 4 + r;
                float z = acc[i][j][r] + bsv;
                if (EPI == EPI_UINIT) {
                    ((__bf16*)outv)[(size_t)row * ldo + col] = (__bf16)z;
                    hxy0[(size_t)row * 1536 + col] = (__bf16)z;
                    hxy0[(size_t)row * 1536 + 768 + col] = (__bf16)0.f;
                } else if (EPI == EPI_GELU) {
                    const float v = 1.5957691216f * z * (1.0f + 0.044715f * z * z);
                    const float sg = 1.0f / (1.0f + __expf(-v));
                    ((__bf16*)outv)[(size_t)row * ldo + col] = (__bf16)(z * sg);
                } else {  // EPI_RES
                    const float zz = res[(size_t)row * ldr + col] + z * gamma[col];
                    ((float*)outv)[(size_t)row * ldo + col] = zz;
                }
            }
        }
    }
}

// ---------------- fused gate GEMM + sigmoid + opponent state update ----------------
// Reads hxy_cur (A, lda=1536, K=1536), writes hxy_next (ping-pong: no cross-block race).
template <bool LAST>
__global__ __launch_bounds__(256) void gate_step(const __bf16* __restrict__ hxy_cur,
                                                 const __bf16* __restrict__ WT_gate,
                                                 const float* __restrict__ b_gate,
                                                 const __bf16* __restrict__ u,
                                                 const float* __restrict__ ad,
                                                 const float* __restrict__ br,
                                                 __bf16* __restrict__ hxy_next) {
    constexpr int BM = 64, BN = 64;
    __shared__ __bf16 As[2 * BM * 32];
    __shared__ __bf16 Bs[2 * BN * 32];
    int mb, nb;
    xcd_swz(mb, nb);
    const int m0 = mb * BM, n0 = nb * BN;

    f32x4 acc[2][2];
    #pragma unroll
    for (int i = 0; i < 2; ++i)
        #pragma unroll
        for (int j = 0; j < 2; ++j)
            acc[i][j] = f32x4{0.f, 0.f, 0.f, 0.f};

    gemm_core<BM, BN>(hxy_cur, 1536, WT_gate, 1536, m0, n0, As, Bs, acc);

    const int l = threadIdx.x & 63;
    const int w = threadIdx.x >> 6;
    const int wm = w >> 1, wn = w & 1;
    const int fr = l & 15;
    const int row0 = m0 + wm * 32;
    const int col0 = n0 + wn * 32;
    #pragma unroll
    for (int i = 0; i < 2; ++i) {
        #pragma unroll
        for (int j = 0; j < 2; ++j) {
            const int col = col0 + j * 16 + fr;
            const float bg = b_gate[col];
            const float av = ad[col];
            const float bv = br[col];
            #pragma unroll
            for (int r = 0; r < 4; ++r) {
                const int row = row0 + i * 16 + (l >> 4) * 4 + r;
                float z = acc[i][j][r] + bg;
                z = 1.0f / (1.0f + __expf(-z));
                const size_t base = (size_t)row * 1536 + col;
                const float hx = (float)hxy_cur[base];
                const float hy = (float)hxy_cur[base + 768];
                const float uf = (float)u[(size_t)row * 768 + col];
                hxy_next[base] = (__bf16)(z * (av * hx - bv * hy) + uf);
                if (!LAST)
                    hxy_next[base + 768] = (__bf16)(z * (bv * hx + av * hy));
            }
        }
    }
}

extern "C" void kernel_launch(void* const* d_in, const int* in_sizes, int n_in,
                              void* d_out, int out_size, void* d_ws, size_t ws_size,
                              hipStream_t stream) {
    (void)in_sizes; (void)n_in; (void)out_size;
    const float* x      = (const float*)d_in[0];
    const float* ln1_s  = (const float*)d_in[1];
    const float* ln1_b  = (const float*)d_in[2];
    const float* W_in   = (const float*)d_in[3];
    const float* b_in   = (const float*)d_in[4];
    const float* W_gate = (const float*)d_in[5];
    const float* b_gate = (const float*)d_in[6];
    const float* a_dec  = (const float*)d_in[7];
    const float* b_rot  = (const float*)d_in[8];
    const float* W_out  = (const float*)d_in[9];
    const float* b_out  = (const float*)d_in[10];
    const float* gamma1 = (const float*)d_in[11];
    const float* ln2_s  = (const float*)d_in[12];
    const float* ln2_b  = (const float*)d_in[13];
    const float* W1     = (const float*)d_in[14];
    const float* b1     = (const float*)d_in[15];
    const float* W2     = (const float*)d_in[16];
    const float* b2     = (const float*)d_in[17];
    const float* gamma2 = (const float*)d_in[18];
    float* out = (float*)d_out;

    // ---- workspace layout (bytes) ----
    if (ws_size < 92000000) return;
    char* w8 = (char*)d_ws;
    __bf16* WT_in   = (__bf16*)(w8);                 // 768x768  bf16
    __bf16* WT_gate = (__bf16*)(w8 + 1179648);       // 768x1536 bf16
    __bf16* WT_out  = (__bf16*)(w8 + 3538944);       // 768x768  bf16
    __bf16* WT1     = (__bf16*)(w8 + 4718592);       // 3072x768 bf16
    __bf16* WT2     = (__bf16*)(w8 + 9437184);       // 768x3072 bf16
    float*  x1      = (float*)(w8 + 14155776);       // NC fp32
    __bf16* xn      = (__bf16*)(w8 + 33423360);      // NC bf16 (both LN outputs)
    __bf16* u       = (__bf16*)(w8 + 43057152);      // NC bf16
    __bf16* hxy_a   = (__bf16*)(w8 + 52690944);      // NROWSx1536 bf16
    __bf16* hxy_b   = (__bf16*)(w8 + 71958528);      // NROWSx1536 bf16
    __bf16* h       = (__bf16*)(w8 + 52690944);      // NROWSx3072 bf16 (overlays hxy, dead by then)

    transpose_all<<<6912, dim3(32, 8), 0, stream>>>(W_in, W_gate, W_out, W1, W2,
                                                    WT_in, WT_gate, WT_out, WT1, WT2);

    const dim3 gC(12, 98);   // N=768 GEMMs: 64x64 tiles, 1176 blocks
    const dim3 gH(24, 49);   // GELU: 128x128, 1176 blocks

    // branch 1
    ln_kernel<<<NROWS, 256, 0, stream>>>(x, ln1_s, ln1_b, xn);
    // u = xn@W_in + b ; hx0 = u ; hy0 = 0 (t=0 step collapsed, init fused)
    mm_bf16<EPI_UINIT, 64, 64><<<gC, 256, 0, stream>>>(xn, 768, WT_in, b_in,
                                                       nullptr, nullptr, 0, u, 768, 768, hxy_a);
    __bf16* cur = hxy_a;
    __bf16* nxt = hxy_b;
    for (int ts = 1; ts < 8; ++ts) {
        if (ts == 7)
            gate_step<true><<<gC, 256, 0, stream>>>(cur, WT_gate, b_gate, u, a_dec, b_rot, nxt);
        else
            gate_step<false><<<gC, 256, 0, stream>>>(cur, WT_gate, b_gate, u, a_dec, b_rot, nxt);
        __bf16* tmp = cur; cur = nxt; nxt = tmp;
    }
    // x1 = x + (hx @ W_out + b_out) * gamma1   (hx = first 768 cols of cur, lda 1536)
    mm_bf16<EPI_RES, 64, 64><<<gC, 256, 0, stream>>>(cur, 1536, WT_out, b_out,
                                                     gamma1, x, 768, x1, 768, 768, nullptr);
    // branch 2
    ln_kernel<<<NROWS, 256, 0, stream>>>(x1, ln2_s, ln2_b, xn);
    mm_bf16<EPI_GELU, 128, 128><<<gH, 256, 0, stream>>>(xn, 768, WT1, b1,
                                                        nullptr, nullptr, 0, h, 3072, 768, nullptr);
    mm_bf16<EPI_RES, 64, 64><<<gC, 256, 0, stream>>>(h, 3072, WT2, b2,
                                                     gamma2, x1, 768, out, 768, 3072, nullptr);
}

// Round 9
// 552.042 us; speedup vs baseline: 1.6074x; 1.0315x over previous
//
#include <hip/hip_runtime.h>
#include <math.h>

typedef __bf16 bf16x8 __attribute__((ext_vector_type(8)));
typedef float  f32x4  __attribute__((ext_vector_type(4)));

#define NROWS 6272
#define CDIM  768
#define HIDD  3072

#define EPI_UINIT 0
#define EPI_GELU  2
#define EPI_RES   3

__device__ __forceinline__ void gload16(const void* g, void* l) {
    __builtin_amdgcn_global_load_lds(
        (const __attribute__((address_space(1))) void*)(uintptr_t)g,
        (__attribute__((address_space(3))) void*)(uintptr_t)l,
        16, 0, 0);
}

template <int N>
__device__ __forceinline__ void waitcnt_vm() {
    if constexpr (N == 0)      asm volatile("s_waitcnt vmcnt(0)" ::: "memory");
    else if constexpr (N == 2) asm volatile("s_waitcnt vmcnt(2)" ::: "memory");
    else if constexpr (N == 4) asm volatile("s_waitcnt vmcnt(4)" ::: "memory");
    else if constexpr (N == 8) asm volatile("s_waitcnt vmcnt(8)" ::: "memory");
    __builtin_amdgcn_sched_barrier(0);   // rule #18: no op may hoist above the wait
}

// m204 bijective XCD-chunked swizzle
__device__ __forceinline__ void xcd_swz(int& m, int& n) {
    const int gx = gridDim.x;
    const int nwg = gx * gridDim.y;
    const int orig = blockIdx.x + gx * blockIdx.y;
    const int q = nwg >> 3, r = nwg & 7;
    const int xcd = orig & 7, loc = orig >> 3;
    const int wg = (xcd < r ? xcd * (q + 1) : r * (q + 1) + (xcd - r) * q) + loc;
    m = wg / gx;
    n = wg % gx;
}

// ---- GEMM core v3: BK=32, 4 LDS buffers, depth-3 counted-vmcnt pipeline ----
// Per iter: vmcnt(2*LPT) [tile kt landed, 2 tiles stay in flight] ; s_barrier ;
// STAGE tile kt+3 into buf[(kt+3)%4] (freed: computed at iter kt-1, barrier proves done) ;
// COMPUTE buf[kt%4].  One barrier/iter, loads get ~3 iterations to land (T3/T4).
// As/Bs sized 4*BM*32 / 4*BN*32. NT must be divisible by 4 (K in {768,1536,3072}).
template <int BM, int BN>
__device__ __forceinline__ void gemm_core(const __bf16* __restrict__ A, int lda,
                                          const __bf16* __restrict__ BT, int K,
                                          int m0, int n0,
                                          __bf16* As, __bf16* Bs,
                                          f32x4 acc[BM / 32][BN / 32]) {
    constexpr int RF  = BM / 32;
    constexpr int CF  = BN / 32;
    constexpr int ASZ = BM * 32;
    constexpr int BSZ = BN * 32;
    constexpr int LPT = BM / 64 + BN / 64;   // loads per thread per tile
    const int t  = threadIdx.x;
    const int w  = t >> 6;
    const int l  = t & 63;
    const int wm = w >> 1, wn = w & 1;
    const int rsub = t >> 2;
    const int ke   = (t & 3) * 8;
    const int fr = l & 15;
    const int kq = (l >> 4) * 8;

    const __bf16* gA = A  + (size_t)(m0 + rsub) * lda + ke;
    const __bf16* gB = BT + (size_t)(n0 + rsub) * K   + ke;

    auto STAGE = [&](int kt, int buf) {
        const int k0 = kt * 32;
        #pragma unroll
        for (int h = 0; h < BM / 64; ++h)
            gload16(gA + (size_t)(h * 64) * lda + k0, As + buf * ASZ + w * 512 + h * 2048);
        #pragma unroll
        for (int h = 0; h < BN / 64; ++h)
            gload16(gB + (size_t)(h * 64) * K + k0, Bs + buf * BSZ + w * 512 + h * 2048);
    };
    auto COMPUTE = [&](int buf) {
        const __bf16* cA = As + buf * ASZ;
        const __bf16* cB = Bs + buf * BSZ;
        bf16x8 av[RF], bv[CF];
        #pragma unroll
        for (int i = 0; i < RF; ++i)
            av[i] = *(const bf16x8*)&cA[(wm * (BM / 2) + i * 16 + fr) * 32 + kq];
        #pragma unroll
        for (int j = 0; j < CF; ++j)
            bv[j] = *(const bf16x8*)&cB[(wn * (BN / 2) + j * 16 + fr) * 32 + kq];
        #pragma unroll
        for (int i = 0; i < RF; ++i)
            #pragma unroll
            for (int j = 0; j < CF; ++j)
                acc[i][j] = __builtin_amdgcn_mfma_f32_16x16x32_bf16(av[i], bv[j], acc[i][j], 0, 0, 0);
    };

    STAGE(0, 0); STAGE(1, 1); STAGE(2, 2);
    const int NT = K >> 5;

    // main loop: iters 0..NT-5 in chunks of 4 (static buffer indices)
    for (int kt = 0; kt + 4 < NT; kt += 4) {
        waitcnt_vm<2 * LPT>(); __builtin_amdgcn_s_barrier();
        STAGE(kt + 3, 3); COMPUTE(0);
        waitcnt_vm<2 * LPT>(); __builtin_amdgcn_s_barrier();
        STAGE(kt + 4, 0); COMPUTE(1);
        waitcnt_vm<2 * LPT>(); __builtin_amdgcn_s_barrier();
        STAGE(kt + 5, 1); COMPUTE(2);
        waitcnt_vm<2 * LPT>(); __builtin_amdgcn_s_barrier();
        STAGE(kt + 6, 2); COMPUTE(3);
    }
    // peeled tail: iters NT-4..NT-1 (buf indices 0,1,2,3 since NT%4==0)
    waitcnt_vm<2 * LPT>(); __builtin_amdgcn_s_barrier();
    STAGE(NT - 1, 3); COMPUTE(0);
    waitcnt_vm<2 * LPT>(); __builtin_amdgcn_s_barrier();
    COMPUTE(1);
    waitcnt_vm<LPT>();     __builtin_amdgcn_s_barrier();
    COMPUTE(2);
    waitcnt_vm<0>();       __builtin_amdgcn_s_barrier();
    COMPUTE(3);
}

// ---------------- all weight transposes in ONE launch ----------------
__global__ __launch_bounds__(256) void transpose_all(const float* __restrict__ W_in,
                                                     const float* __restrict__ W_gate,
                                                     const float* __restrict__ W_out,
                                                     const float* __restrict__ W1,
                                                     const float* __restrict__ W2,
                                                     __bf16* __restrict__ WT_in,
                                                     __bf16* __restrict__ WT_gate,
                                                     __bf16* __restrict__ WT_out,
                                                     __bf16* __restrict__ WT1,
                                                     __bf16* __restrict__ WT2) {
    const int bid = blockIdx.x;
    const float* W; __bf16* WT; int K, N, gx, local;
    if (bid < 576)        { W = W_in;   WT = WT_in;   K = 768;  N = 768;  gx = 24; local = bid; }
    else if (bid < 1728)  { W = W_gate; WT = WT_gate; K = 1536; N = 768;  gx = 24; local = bid - 576; }
    else if (bid < 2304)  { W = W_out;  WT = WT_out;  K = 768;  N = 768;  gx = 24; local = bid - 1728; }
    else if (bid < 4608)  { W = W1;     WT = WT1;     K = 768;  N = 3072; gx = 96; local = bid - 2304; }
    else                  { W = W2;     WT = WT2;     K = 3072; N = 768;  gx = 24; local = bid - 4608; }
    const int nb = (local % gx) * 32;
    const int kb = (local / gx) * 32;

    __shared__ float tile[32][33];
    const int tx = threadIdx.x, ty = threadIdx.y;
    #pragma unroll
    for (int r = 0; r < 4; ++r)
        tile[ty + r * 8][tx] = W[(size_t)(kb + ty + r * 8) * N + nb + tx];
    __syncthreads();
    #pragma unroll
    for (int r = 0; r < 4; ++r)
        WT[(size_t)(nb + ty + r * 8) * K + kb + tx] = (__bf16)tile[tx][ty + r * 8];
}

// ---------------- LayerNorm (fp32 in, bf16 out) ----------------
__global__ __launch_bounds__(256) void ln_kernel(const float* __restrict__ x,
                                                 const float* __restrict__ sc,
                                                 const float* __restrict__ bi,
                                                 __bf16* __restrict__ o) {
    const int row = blockIdx.x;
    const float* xr = x + (size_t)row * CDIM;
    __bf16* orow = o + (size_t)row * CDIM;
    const int t = threadIdx.x;

    float v0 = xr[t], v1 = xr[t + 256], v2 = xr[t + 512];
    float s = v0 + v1 + v2;

    __shared__ float sm[8];
    #pragma unroll
    for (int off = 32; off > 0; off >>= 1) s += __shfl_xor(s, off);
    const int wid = t >> 6, lane = t & 63;
    if (lane == 0) sm[wid] = s;
    __syncthreads();
    const float mu = (sm[0] + sm[1] + sm[2] + sm[3]) * (1.0f / 768.0f);

    const float d0 = v0 - mu, d1 = v1 - mu, d2 = v2 - mu;
    float s2 = d0 * d0 + d1 * d1 + d2 * d2;
    #pragma unroll
    for (int off = 32; off > 0; off >>= 1) s2 += __shfl_xor(s2, off);
    if (lane == 0) sm[4 + wid] = s2;
    __syncthreads();
    const float var = (sm[4] + sm[5] + sm[6] + sm[7]) * (1.0f / 768.0f);
    const float r = rsqrtf(var + 1e-6f);

    orow[t]       = (__bf16)(d0 * r * sc[t]       + bi[t]);
    orow[t + 256] = (__bf16)(d1 * r * sc[t + 256] + bi[t + 256]);
    orow[t + 512] = (__bf16)(d2 * r * sc[t + 512] + bi[t + 512]);
}

// ---------------- generic MFMA GEMM with epilogues ----------------
// EPI_UINIT: out(bf16)=z AND hxy0 hx=z, hy=0 (fused init_state)
// EPI_GELU : out(bf16)=z*sigmoid(2c(z+0.044715 z^3))  (tanh-gelu via sigmoid)
// EPI_RES  : out(f32)=res + z*gamma
template <int EPI, int BM, int BN>
__global__ __launch_bounds__(256) void mm_bf16(const __bf16* __restrict__ A, int lda,
                                               const __bf16* __restrict__ BT,
                                               const float* __restrict__ bias,
                                               const float* __restrict__ gamma,
                                               const float* __restrict__ res, int ldr,
                                               void* __restrict__ outv, int ldo,
                                               int K, __bf16* __restrict__ hxy0) {
    constexpr int RF = BM / 32;
    constexpr int CF = BN / 32;
    __shared__ __bf16 As[4 * BM * 32];
    __shared__ __bf16 Bs[4 * BN * 32];
    int mb, nb;
    xcd_swz(mb, nb);
    const int m0 = mb * BM, n0 = nb * BN;

    f32x4 acc[RF][CF];
    #pragma unroll
    for (int i = 0; i < RF; ++i)
        #pragma unroll
        for (int j = 0; j < CF; ++j)
            acc[i][j] = f32x4{0.f, 0.f, 0.f, 0.f};

    gemm_core<BM, BN>(A, lda, BT, K, m0, n0, As, Bs, acc);

    const int l = threadIdx.x & 63;
    const int w = threadIdx.x >> 6;
    const int wm = w >> 1, wn = w & 1;
    const int fr = l & 15;
    const int row0 = m0 + wm * (BM / 2);
    const int col0 = n0 + wn * (BN / 2);
    #pragma unroll
    for (int i = 0; i < RF; ++i) {
        #pragma unroll
        for (int j = 0; j < CF; ++j) {
            const int col = col0 + j * 16 + fr;
            const float bsv = bias[col];
            #pragma unroll
            for (int r = 0; r < 4; ++r) {
                const int row = row0 + i * 16 + (l >> 4) * 4 + r;
                float z = acc[i][j][r] + bsv;
                if (EPI == EPI_UINIT) {
                    ((__bf16*)outv)[(size_t)row * ldo + col] = (__bf16)z;
                    hxy0[(size_t)row * 1536 + col] = (__bf16)z;
                    hxy0[(size_t)row * 1536 + 768 + col] = (__bf16)0.f;
                } else if (EPI == EPI_GELU) {
                    const float v = 1.5957691216f * z * (1.0f + 0.044715f * z * z);
                    const float sg = 1.0f / (1.0f + __expf(-v));
                    ((__bf16*)outv)[(size_t)row * ldo + col] = (__bf16)(z * sg);
                } else {  // EPI_RES
                    const float zz = res[(size_t)row * ldr + col] + z * gamma[col];
                    ((float*)outv)[(size_t)row * ldo + col] = zz;
                }
            }
        }
    }
}

// ---------------- fused gate GEMM + sigmoid + opponent state update ----------------
// Reads hxy_cur (A, lda=1536, K=1536), writes hxy_next (ping-pong: no cross-block race).
template <bool LAST>
__global__ __launch_bounds__(256) void gate_step(const __bf16* __restrict__ hxy_cur,
                                                 const __bf16* __restrict__ WT_gate,
                                                 const float* __restrict__ b_gate,
                                                 const __bf16* __restrict__ u,
                                                 const float* __restrict__ ad,
                                                 const float* __restrict__ br,
                                                 __bf16* __restrict__ hxy_next) {
    constexpr int BM = 64, BN = 64;
    __shared__ __bf16 As[4 * BM * 32];
    __shared__ __bf16 Bs[4 * BN * 32];
    int mb, nb;
    xcd_swz(mb, nb);
    const int m0 = mb * BM, n0 = nb * BN;

    f32x4 acc[2][2];
    #pragma unroll
    for (int i = 0; i < 2; ++i)
        #pragma unroll
        for (int j = 0; j < 2; ++j)
            acc[i][j] = f32x4{0.f, 0.f, 0.f, 0.f};

    gemm_core<BM, BN>(hxy_cur, 1536, WT_gate, 1536, m0, n0, As, Bs, acc);

    const int l = threadIdx.x & 63;
    const int w = threadIdx.x >> 6;
    const int wm = w >> 1, wn = w & 1;
    const int fr = l & 15;
    const int row0 = m0 + wm * 32;
    const int col0 = n0 + wn * 32;
    #pragma unroll
    for (int i = 0; i < 2; ++i) {
        #pragma unroll
        for (int j = 0; j < 2; ++j) {
            const int col = col0 + j * 16 + fr;
            const float bg = b_gate[col];
            const float av = ad[col];
            const float bv = br[col];
            #pragma unroll
            for (int r = 0; r < 4; ++r) {
                const int row = row0 + i * 16 + (l >> 4) * 4 + r;
                float z = acc[i][j][r] + bg;
                z = 1.0f / (1.0f + __expf(-z));
                const size_t base = (size_t)row * 1536 + col;
                const float hx = (float)hxy_cur[base];
                const float hy = (float)hxy_cur[base + 768];
                const float uf = (float)u[(size_t)row * 768 + col];
                hxy_next[base] = (__bf16)(z * (av * hx - bv * hy) + uf);
                if (!LAST)
                    hxy_next[base + 768] = (__bf16)(z * (bv * hx + av * hy));
            }
        }
    }
}

extern "C" void kernel_launch(void* const* d_in, const int* in_sizes, int n_in,
                              void* d_out, int out_size, void* d_ws, size_t ws_size,
                              hipStream_t stream) {
    (void)in_sizes; (void)n_in; (void)out_size;
    const float* x      = (const float*)d_in[0];
    const float* ln1_s  = (const float*)d_in[1];
    const float* ln1_b  = (const float*)d_in[2];
    const float* W_in   = (const float*)d_in[3];
    const float* b_in   = (const float*)d_in[4];
    const float* W_gate = (const float*)d_in[5];
    const float* b_gate = (const float*)d_in[6];
    const float* a_dec  = (const float*)d_in[7];
    const float* b_rot  = (const float*)d_in[8];
    const float* W_out  = (const float*)d_in[9];
    const float* b_out  = (const float*)d_in[10];
    const float* gamma1 = (const float*)d_in[11];
    const float* ln2_s  = (const float*)d_in[12];
    const float* ln2_b  = (const float*)d_in[13];
    const float* W1     = (const float*)d_in[14];
    const float* b1     = (const float*)d_in[15];
    const float* W2     = (const float*)d_in[16];
    const float* b2     = (const float*)d_in[17];
    const float* gamma2 = (const float*)d_in[18];
    float* out = (float*)d_out;

    // ---- workspace layout (bytes) ----
    if (ws_size < 92000000) return;
    char* w8 = (char*)d_ws;
    __bf16* WT_in   = (__bf16*)(w8);                 // 768x768  bf16
    __bf16* WT_gate = (__bf16*)(w8 + 1179648);       // 768x1536 bf16
    __bf16* WT_out  = (__bf16*)(w8 + 3538944);       // 768x768  bf16
    __bf16* WT1     = (__bf16*)(w8 + 4718592);       // 3072x768 bf16
    __bf16* WT2     = (__bf16*)(w8 + 9437184);       // 768x3072 bf16
    float*  x1      = (float*)(w8 + 14155776);       // NC fp32
    __bf16* xn      = (__bf16*)(w8 + 33423360);      // NC bf16 (both LN outputs)
    __bf16* u       = (__bf16*)(w8 + 43057152);      // NC bf16
    __bf16* hxy_a   = (__bf16*)(w8 + 52690944);      // NROWSx1536 bf16
    __bf16* hxy_b   = (__bf16*)(w8 + 71958528);      // NROWSx1536 bf16
    __bf16* h       = (__bf16*)(w8 + 52690944);      // NROWSx3072 bf16 (overlays hxy, dead by then)

    transpose_all<<<6912, dim3(32, 8), 0, stream>>>(W_in, W_gate, W_out, W1, W2,
                                                    WT_in, WT_gate, WT_out, WT1, WT2);

    const dim3 gC(12, 98);   // N=768 GEMMs: 64x64 tiles, 1176 blocks
    const dim3 gH(24, 49);   // GELU: 128x128, 1176 blocks

    // branch 1
    ln_kernel<<<NROWS, 256, 0, stream>>>(x, ln1_s, ln1_b, xn);
    // u = xn@W_in + b ; hx0 = u ; hy0 = 0 (t=0 step collapsed, init fused)
    mm_bf16<EPI_UINIT, 64, 64><<<gC, 256, 0, stream>>>(xn, 768, WT_in, b_in,
                                                       nullptr, nullptr, 0, u, 768, 768, hxy_a);
    __bf16* cur = hxy_a;
    __bf16* nxt = hxy_b;
    for (int ts = 1; ts < 8; ++ts) {
        if (ts == 7)
            gate_step<true><<<gC, 256, 0, stream>>>(cur, WT_gate, b_gate, u, a_dec, b_rot, nxt);
        else
            gate_step<false><<<gC, 256, 0, stream>>>(cur, WT_gate, b_gate, u, a_dec, b_rot, nxt);
        __bf16* tmp = cur; cur = nxt; nxt = tmp;
    }
    // x1 = x + (hx @ W_out + b_out) * gamma1   (hx = first 768 cols of cur, lda 1536)
    mm_bf16<EPI_RES, 64, 64><<<gC, 256, 0, stream>>>(cur, 1536, WT_out, b_out,
                                                     gamma1, x, 768, x1, 768, 768, nullptr);
    // branch 2
    ln_kernel<<<NROWS, 256, 0, stream>>>(x1, ln2_s, ln2_b, xn);
    mm_bf16<EPI_GELU, 128, 128><<<gH, 256, 0, stream>>>(xn, 768, WT1, b1,
                                                        nullptr, nullptr, 0, h, 3072, 768, nullptr);
    mm_bf16<EPI_RES, 64, 64><<<gC, 256, 0, stream>>>(h, 3072, WT2, b2,
                                                     gamma2, x1, 768, out, 768, 3072, nullptr);
}

// Round 11
// 549.292 us; speedup vs baseline: 1.6155x; 1.0050x over previous
//
#include <hip/hip_runtime.h>
#include <math.h>

typedef __bf16 bf16x8 __attribute__((ext_vector_type(8)));
typedef float  f32x4  __attribute__((ext_vector_type(4)));

#define NROWS 6272
#define CDIM  768
#define HIDD  3072

#define EPI_UINIT 0
#define EPI_GELU  2
#define EPI_RES   3

__device__ __forceinline__ void gload16(const void* g, void* l) {
    __builtin_amdgcn_global_load_lds(
        (const __attribute__((address_space(1))) void*)(uintptr_t)g,
        (__attribute__((address_space(3))) void*)(uintptr_t)l,
        16, 0, 0);
}

template <int N>
__device__ __forceinline__ void waitcnt_vm() {
    if constexpr (N == 0)      asm volatile("s_waitcnt vmcnt(0)" ::: "memory");
    else if constexpr (N == 2) asm volatile("s_waitcnt vmcnt(2)" ::: "memory");
    else if constexpr (N == 4) asm volatile("s_waitcnt vmcnt(4)" ::: "memory");
    else if constexpr (N == 8) asm volatile("s_waitcnt vmcnt(8)" ::: "memory");
    __builtin_amdgcn_sched_barrier(0);   // rule #18: no op may hoist above the wait
}

// m204 bijective XCD-chunked swizzle
__device__ __forceinline__ void xcd_swz(int& m, int& n) {
    const int gx = gridDim.x;
    const int nwg = gx * gridDim.y;
    const int orig = blockIdx.x + gx * blockIdx.y;
    const int q = nwg >> 3, r = nwg & 7;
    const int xcd = orig & 7, loc = orig >> 3;
    const int wg = (xcd < r ? xcd * (q + 1) : r * (q + 1) + (xcd - r) * q) + loc;
    m = wg / gx;
    n = wg % gx;
}

// ---- GEMM core v4: BK=32, 4 LDS buffers, depth-3 counted vmcnt, T2 granule swizzle ----
// LDS bank fix (rule #21 both-sides): granule g' = g ^ ((row>>1)&3), 16B granules, 4/row.
//  - write side: LDS stays LINEAR (global_load_lds requirement); the global SOURCE
//    k-granule for thread t (=granule t) is (t&3) ^ ((t>>3)&3); row = t>>2 unchanged.
//  - read side: fragment element offset = row*32 + ((q4 ^ ((fr>>1)&3)) * 8).
// Rows 0..7 at fixed q4 hit bank classes {0,4,1,5,2,6,3,7} -> 16-row col-slice = 2-way = free.
template <int BM, int BN>
__device__ __forceinline__ void gemm_core(const __bf16* __restrict__ A, int lda,
                                          const __bf16* __restrict__ BT, int K,
                                          int m0, int n0,
                                          __bf16* As, __bf16* Bs,
                                          f32x4 acc[BM / 32][BN / 32]) {
    constexpr int RF  = BM / 32;
    constexpr int CF  = BN / 32;
    constexpr int ASZ = BM * 32;
    constexpr int BSZ = BN * 32;
    constexpr int LPT = BM / 64 + BN / 64;   // loads per thread per tile
    const int t  = threadIdx.x;
    const int w  = t >> 6;
    const int l  = t & 63;
    const int wm = w >> 1, wn = w & 1;
    const int rsub = t >> 2;                            // staged row (per 64-row half)
    const int ke   = ((t & 3) ^ ((t >> 3) & 3)) * 8;    // pre-swizzled source k-granule
    const int fr = l & 15;
    const int q4 = l >> 4;
    const int sw = (fr >> 1) & 3;                 // read-side granule XOR
    const int kq = (q4 ^ sw) * 8;                 // swizzled element offset within row

    const __bf16* gA = A  + (size_t)(m0 + rsub) * lda + ke;
    const __bf16* gB = BT + (size_t)(n0 + rsub) * K   + ke;

    auto STAGE = [&](int kt, int buf) {
        const int k0 = kt * 32;
        #pragma unroll
        for (int h = 0; h < BM / 64; ++h)
            gload16(gA + (size_t)(h * 64) * lda + k0, As + buf * ASZ + w * 512 + h * 2048);
        #pragma unroll
        for (int h = 0; h < BN / 64; ++h)
            gload16(gB + (size_t)(h * 64) * K + k0, Bs + buf * BSZ + w * 512 + h * 2048);
    };
    auto COMPUTE = [&](int buf) {
        const __bf16* cA = As + buf * ASZ;
        const __bf16* cB = Bs + buf * BSZ;
        bf16x8 av[RF], bv[CF];
        #pragma unroll
        for (int i = 0; i < RF; ++i)
            av[i] = *(const bf16x8*)&cA[(wm * (BM / 2) + i * 16 + fr) * 32 + kq];
        #pragma unroll
        for (int j = 0; j < CF; ++j)
            bv[j] = *(const bf16x8*)&cB[(wn * (BN / 2) + j * 16 + fr) * 32 + kq];
        #pragma unroll
        for (int i = 0; i < RF; ++i)
            #pragma unroll
            for (int j = 0; j < CF; ++j)
                acc[i][j] = __builtin_amdgcn_mfma_f32_16x16x32_bf16(av[i], bv[j], acc[i][j], 0, 0, 0);
    };

    STAGE(0, 0); STAGE(1, 1); STAGE(2, 2);
    const int NT = K >> 5;

    // main loop: chunks of 4 (static buffer indices; NT % 4 == 0 for K in {768,1536,3072})
    for (int kt = 0; kt + 4 < NT; kt += 4) {
        waitcnt_vm<2 * LPT>(); __builtin_amdgcn_s_barrier();
        STAGE(kt + 3, 3); COMPUTE(0);
        waitcnt_vm<2 * LPT>(); __builtin_amdgcn_s_barrier();
        STAGE(kt + 4, 0); COMPUTE(1);
        waitcnt_vm<2 * LPT>(); __builtin_amdgcn_s_barrier();
        STAGE(kt + 5, 1); COMPUTE(2);
        waitcnt_vm<2 * LPT>(); __builtin_amdgcn_s_barrier();
        STAGE(kt + 6, 2); COMPUTE(3);
    }
    // peeled tail: iters NT-4..NT-1
    waitcnt_vm<2 * LPT>(); __builtin_amdgcn_s_barrier();
    STAGE(NT - 1, 3); COMPUTE(0);
    waitcnt_vm<2 * LPT>(); __builtin_amdgcn_s_barrier();
    COMPUTE(1);
    waitcnt_vm<LPT>();     __builtin_amdgcn_s_barrier();
    COMPUTE(2);
    waitcnt_vm<0>();       __builtin_amdgcn_s_barrier();
    COMPUTE(3);
}

// ---------------- all weight transposes in ONE launch ----------------
__global__ __launch_bounds__(256) void transpose_all(const float* __restrict__ W_in,
                                                     const float* __restrict__ W_gate,
                                                     const float* __restrict__ W_out,
                                                     const float* __restrict__ W1,
                                                     const float* __restrict__ W2,
                                                     __bf16* __restrict__ WT_in,
                                                     __bf16* __restrict__ WT_gate,
                                                     __bf16* __restrict__ WT_out,
                                                     __bf16* __restrict__ WT1,
                                                     __bf16* __restrict__ WT2) {
    const int bid = blockIdx.x;
    const float* W; __bf16* WT; int K, N, gx, local;
    if (bid < 576)        { W = W_in;   WT = WT_in;   K = 768;  N = 768;  gx = 24; local = bid; }
    else if (bid < 1728)  { W = W_gate; WT = WT_gate; K = 1536; N = 768;  gx = 24; local = bid - 576; }
    else if (bid < 2304)  { W = W_out;  WT = WT_out;  K = 768;  N = 768;  gx = 24; local = bid - 1728; }
    else if (bid < 4608)  { W = W1;     WT = WT1;     K = 768;  N = 3072; gx = 96; local = bid - 2304; }
    else                  { W = W2;     WT = WT2;     K = 3072; N = 768;  gx = 24; local = bid - 4608; }
    const int nb = (local % gx) * 32;
    const int kb = (local / gx) * 32;

    __shared__ float tile[32][33];
    const int tx = threadIdx.x, ty = threadIdx.y;
    #pragma unroll
    for (int r = 0; r < 4; ++r)
        tile[ty + r * 8][tx] = W[(size_t)(kb + ty + r * 8) * N + nb + tx];
    __syncthreads();
    #pragma unroll
    for (int r = 0; r < 4; ++r)
        WT[(size_t)(nb + ty + r * 8) * K + kb + tx] = (__bf16)tile[tx][ty + r * 8];
}

// ---------------- LayerNorm (fp32 in, bf16 out) ----------------
__global__ __launch_bounds__(256) void ln_kernel(const float* __restrict__ x,
                                                 const float* __restrict__ sc,
                                                 const float* __restrict__ bi,
                                                 __bf16* __restrict__ o) {
    const int row = blockIdx.x;
    const float* xr = x + (size_t)row * CDIM;
    __bf16* orow = o + (size_t)row * CDIM;
    const int t = threadIdx.x;

    float v0 = xr[t], v1 = xr[t + 256], v2 = xr[t + 512];
    float s = v0 + v1 + v2;

    __shared__ float sm[8];
    #pragma unroll
    for (int off = 32; off > 0; off >>= 1) s += __shfl_xor(s, off);
    const int wid = t >> 6, lane = t & 63;
    if (lane == 0) sm[wid] = s;
    __syncthreads();
    const float mu = (sm[0] + sm[1] + sm[2] + sm[3]) * (1.0f / 768.0f);

    const float d0 = v0 - mu, d1 = v1 - mu, d2 = v2 - mu;
    float s2 = d0 * d0 + d1 * d1 + d2 * d2;
    #pragma unroll
    for (int off = 32; off > 0; off >>= 1) s2 += __shfl_xor(s2, off);
    if (lane == 0) sm[4 + wid] = s2;
    __syncthreads();
    const float var = (sm[4] + sm[5] + sm[6] + sm[7]) * (1.0f / 768.0f);
    const float r = rsqrtf(var + 1e-6f);

    orow[t]       = (__bf16)(d0 * r * sc[t]       + bi[t]);
    orow[t + 256] = (__bf16)(d1 * r * sc[t + 256] + bi[t + 256]);
    orow[t + 512] = (__bf16)(d2 * r * sc[t + 512] + bi[t + 512]);
}

// ---------------- generic MFMA GEMM with epilogues ----------------
// EPI_UINIT: out(bf16)=z AND hxy0 hx=z, hy=0 (fused init_state)
// EPI_GELU : out(bf16)=z*sigmoid(2c(z+0.044715 z^3))  (tanh-gelu via sigmoid)
// EPI_RES  : out(f32)=res + z*gamma
template <int EPI, int BM, int BN>
__global__ __launch_bounds__(256) void mm_bf16(const __bf16* __restrict__ A, int lda,
                                               const __bf16* __restrict__ BT,
                                               const float* __restrict__ bias,
                                               const float* __restrict__ gamma,
                                               const float* __restrict__ res, int ldr,
                                               void* __restrict__ outv, int ldo,
                                               int K, __bf16* __restrict__ hxy0) {
    constexpr int RF = BM / 32;
    constexpr int CF = BN / 32;
    __shared__ __bf16 As[4 * BM * 32];
    __shared__ __bf16 Bs[4 * BN * 32];
    int mb, nb;
    xcd_swz(mb, nb);
    const int m0 = mb * BM, n0 = nb * BN;

    f32x4 acc[RF][CF];
    #pragma unroll
    for (int i = 0; i < RF; ++i)
        #pragma unroll
        for (int j = 0; j < CF; ++j)
            acc[i][j] = f32x4{0.f, 0.f, 0.f, 0.f};

    gemm_core<BM, BN>(A, lda, BT, K, m0, n0, As, Bs, acc);

    const int l = threadIdx.x & 63;
    const int w = threadIdx.x >> 6;
    const int wm = w >> 1, wn = w & 1;
    const int fr = l & 15;
    const int row0 = m0 + wm * (BM / 2);
    const int col0 = n0 + wn * (BN / 2);
    #pragma unroll
    for (int i = 0; i < RF; ++i) {
        #pragma unroll
        for (int j = 0; j < CF; ++j) {
            const int col = col0 + j * 16 + fr;
            const float bsv = bias[col];
            #pragma unroll
            for (int r = 0; r < 4; ++r) {
                const int row = row0 + i * 16 + (l >> 4) * 4 + r;
                float z = acc[i][j][r] + bsv;
                if (EPI == EPI_UINIT) {
                    ((__bf16*)outv)[(size_t)row * ldo + col] = (__bf16)z;
                    hxy0[(size_t)row * 1536 + col] = (__bf16)z;
                    hxy0[(size_t)row * 1536 + 768 + col] = (__bf16)0.f;
                } else if (EPI == EPI_GELU) {
                    const float v = 1.5957691216f * z * (1.0f + 0.044715f * z * z);
                    const float sg = 1.0f / (1.0f + __expf(-v));
                    ((__bf16*)outv)[(size_t)row * ldo + col] = (__bf16)(z * sg);
                } else {  // EPI_RES
                    const float zz = res[(size_t)row * ldr + col] + z * gamma[col];
                    ((float*)outv)[(size_t)row * ldo + col] = zz;
                }
            }
        }
    }
}

// ---------------- fused gate GEMM + sigmoid + opponent state update ----------------
// Reads hxy_cur (A, lda=1536, K=1536), writes hxy_next (ping-pong: no cross-block race).
template <bool LAST>
__global__ __launch_bounds__(256) void gate_step(const __bf16* __restrict__ hxy_cur,
                                                 const __bf16* __restrict__ WT_gate,
                                                 const float* __restrict__ b_gate,
                                                 const __bf16* __restrict__ u,
                                                 const float* __restrict__ ad,
                                                 const float* __restrict__ br,
                                                 __bf16* __restrict__ hxy_next) {
    constexpr int BM = 64, BN = 64;
    __shared__ __bf16 As[4 * BM * 32];
    __shared__ __bf16 Bs[4 * BN * 32];
    int mb, nb;
    xcd_swz(mb, nb);
    const int m0 = mb * BM, n0 = nb * BN;

    f32x4 acc[2][2];
    #pragma unroll
    for (int i = 0; i < 2; ++i)
        #pragma unroll
        for (int j = 0; j < 2; ++j)
            acc[i][j] = f32x4{0.f, 0.f, 0.f, 0.f};

    gemm_core<BM, BN>(hxy_cur, 1536, WT_gate, 1536, m0, n0, As, Bs, acc);

    const int l = threadIdx.x & 63;
    const int w = threadIdx.x >> 6;
    const int wm = w >> 1, wn = w & 1;
    const int fr = l & 15;
    const int row0 = m0 + wm * 32;
    const int col0 = n0 + wn * 32;
    #pragma unroll
    for (int i = 0; i < 2; ++i) {
        #pragma unroll
        for (int j = 0; j < 2; ++j) {
            const int col = col0 + j * 16 + fr;
            const float bg = b_gate[col];
            const float av = ad[col];
            const float bv = br[col];
            #pragma unroll
            for (int r = 0; r < 4; ++r) {
                const int row = row0 + i * 16 + (l >> 4) * 4 + r;
                float z = acc[i][j][r] + bg;
                z = 1.0f / (1.0f + __expf(-z));
                const size_t base = (size_t)row * 1536 + col;
                const float hx = (float)hxy_cur[base];
                const float hy = (float)hxy_cur[base + 768];
                const float uf = (float)u[(size_t)row * 768 + col];
                hxy_next[base] = (__bf16)(z * (av * hx - bv * hy) + uf);
                if (!LAST)
                    hxy_next[base + 768] = (__bf16)(z * (bv * hx + av * hy));
            }
        }
    }
}

extern "C" void kernel_launch(void* const* d_in, const int* in_sizes, int n_in,
                              void* d_out, int out_size, void* d_ws, size_t ws_size,
                              hipStream_t stream) {
    (void)in_sizes; (void)n_in; (void)out_size;
    const float* x      = (const float*)d_in[0];
    const float* ln1_s  = (const float*)d_in[1];
    const float* ln1_b  = (const float*)d_in[2];
    const float* W_in   = (const float*)d_in[3];
    const float* b_in   = (const float*)d_in[4];
    const float* W_gate = (const float*)d_in[5];
    const float* b_gate = (const float*)d_in[6];
    const float* a_dec  = (const float*)d_in[7];
    const float* b_rot  = (const float*)d_in[8];
    const float* W_out  = (const float*)d_in[9];
    const float* b_out  = (const float*)d_in[10];
    const float* gamma1 = (const float*)d_in[11];
    const float* ln2_s  = (const float*)d_in[12];
    const float* ln2_b  = (const float*)d_in[13];
    const float* W1     = (const float*)d_in[14];
    const float* b1     = (const float*)d_in[15];
    const float* W2     = (const float*)d_in[16];
    const float* b2     = (const float*)d_in[17];
    const float* gamma2 = (const float*)d_in[18];
    float* out = (float*)d_out;

    // ---- workspace layout (bytes) ----
    if (ws_size < 92000000) return;
    char* w8 = (char*)d_ws;
    __bf16* WT_in   = (__bf16*)(w8);                 // 768x768  bf16
    __bf16* WT_gate = (__bf16*)(w8 + 1179648);       // 768x1536 bf16
    __bf16* WT_out  = (__bf16*)(w8 + 3538944);       // 768x768  bf16
    __bf16* WT1     = (__bf16*)(w8 + 4718592);       // 3072x768 bf16
    __bf16* WT2     = (__bf16*)(w8 + 9437184);       // 768x3072 bf16
    float*  x1      = (float*)(w8 + 14155776);       // NC fp32
    __bf16* xn      = (__bf16*)(w8 + 33423360);      // NC bf16 (both LN outputs)
    __bf16* u       = (__bf16*)(w8 + 43057152);      // NC bf16
    __bf16* hxy_a   = (__bf16*)(w8 + 52690944);      // NROWSx1536 bf16
    __bf16* hxy_b   = (__bf16*)(w8 + 71958528);      // NROWSx1536 bf16
    __bf16* h       = (__bf16*)(w8 + 52690944);      // NROWSx3072 bf16 (overlays hxy, dead by then)

    transpose_all<<<6912, dim3(32, 8), 0, stream>>>(W_in, W_gate, W_out, W1, W2,
                                                    WT_in, WT_gate, WT_out, WT1, WT2);

    const dim3 gC(12, 98);   // N=768 GEMMs: 64x64 tiles, 1176 blocks
    const dim3 gH(24, 49);   // GELU: 128x128, 1176 blocks

    // branch 1
    ln_kernel<<<NROWS, 256, 0, stream>>>(x, ln1_s, ln1_b, xn);
    // u = xn@W_in + b ; hx0 = u ; hy0 = 0 (t=0 step collapsed, init fused)
    mm_bf16<EPI_UINIT, 64, 64><<<gC, 256, 0, stream>>>(xn, 768, WT_in, b_in,
                                                       nullptr, nullptr, 0, u, 768, 768, hxy_a);
    __bf16* cur = hxy_a;
    __bf16* nxt = hxy_b;
    for (int ts = 1; ts < 8; ++ts) {
        if (ts == 7)
            gate_step<true><<<gC, 256, 0, stream>>>(cur, WT_gate, b_gate, u, a_dec, b_rot, nxt);
        else
            gate_step<false><<<gC, 256, 0, stream>>>(cur, WT_gate, b_gate, u, a_dec, b_rot, nxt);
        __bf16* tmp = cur; cur = nxt; nxt = tmp;
    }
    // x1 = x + (hx @ W_out + b_out) * gamma1   (hx = first 768 cols of cur, lda 1536)
    mm_bf16<EPI_RES, 64, 64><<<gC, 256, 0, stream>>>(cur, 1536, WT_out, b_out,
                                                     gamma1, x, 768, x1, 768, 768, nullptr);
    // branch 2
    ln_kernel<<<NROWS, 256, 0, stream>>>(x1, ln2_s, ln2_b, xn);
    mm_bf16<EPI_GELU, 128, 128><<<gH, 256, 0, stream>>>(xn, 768, WT1, b1,
                                                        nullptr, nullptr, 0, h, 3072, 768, nullptr);
    mm_bf16<EPI_RES, 64, 64><<<gC, 256, 0, stream>>>(h, 3072, WT2, b2,
                                                     gamma2, x1, 768, out, 768, 3072, nullptr);
}